// Round 2
// baseline (8738.327 us; speedup 1.0000x reference)
//
#include <hip/hip_runtime.h>
#include <hip/hip_bf16.h>
#include <math.h>

#define NB     64
#define LL     2048
#define DD     256
#define NNODE  256     // G*K
#define NSTEPS 32

__device__ __forceinline__ float geluf(float x){ return 0.5f*x*(1.0f+erff(x*0.70710678118654752440f)); }

// 32-row FMA micro-kernel: acc[r] += A[k][r] * w, A row is 32 contiguous floats in LDS
__device__ __forceinline__ void fma32(const float* Arow, float w, float* acc){
  const float4* ap = (const float4*)Arow;
  #pragma unroll
  for(int i=0;i<8;i++){
    float4 a = ap[i];
    acc[i*4+0] += a.x*w; acc[i*4+1] += a.y*w;
    acc[i*4+2] += a.z*w; acc[i*4+3] += a.w*w;
  }
}
__device__ __forceinline__ void fma32_2(const float* Arow, float w0, float w1, float* acc0, float* acc1){
  const float4* ap = (const float4*)Arow;
  #pragma unroll
  for(int i=0;i<8;i++){
    float4 a = ap[i];
    acc0[i*4+0] += a.x*w0; acc0[i*4+1] += a.y*w0;
    acc0[i*4+2] += a.z*w0; acc0[i*4+3] += a.w*w0;
    acc1[i*4+0] += a.x*w1; acc1[i*4+1] += a.y*w1;
    acc1[i*4+2] += a.z*w1; acc1[i*4+3] += a.w*w1;
  }
}

// ---------------- K1: P tables: rows 0..49 src-part, 50..51 rel-part(+eb1), 52..101 tgt-part
__global__ __launch_bounds__(256) void k_precompute(const float* __restrict__ ne,
    const float* __restrict__ re, const float* __restrict__ ew1, const float* __restrict__ eb1,
    float* __restrict__ P){
  __shared__ float a[256];
  int row = blockIdx.x, j = threadIdx.x;
  const float* vec; const float* W;
  if(row < 50){ vec = ne + row*256; W = ew1; }
  else if(row < 52){ vec = re + (row-50)*256; W = ew1 + 256*256; }
  else { vec = ne + (row-52)*256; W = ew1 + 512*256; }
  a[j] = vec[j];
  __syncthreads();
  float acc = 0.f;
  for(int k=0;k<256;k++) acc += a[k]*W[k*256 + j];
  if(row >= 50 && row < 52) acc += eb1[j];
  P[row*256 + j] = acc;
}

// ---------------- K2: q[b] = MLP2(concat(ne[qsrc], ne[qtgt]))
__global__ __launch_bounds__(256) void k_query(const int* __restrict__ qsrc, const int* __restrict__ qtgt,
    const float* __restrict__ ne, const float* __restrict__ qw1, const float* __restrict__ qb1,
    const float* __restrict__ qw2, const float* __restrict__ qb2, float* __restrict__ qv){
  __shared__ float a[512];
  __shared__ float h[256];
  int b = blockIdx.x, j = threadIdx.x;
  int s = min(max(qsrc[b],0),49), t = min(max(qtgt[b],0),49);
  a[j]     = ne[s*256 + j];
  a[256+j] = ne[t*256 + j];
  __syncthreads();
  float acc = qb1[j];
  for(int k=0;k<512;k++) acc += a[k]*qw1[k*256+j];
  h[j] = geluf(acc);
  __syncthreads();
  float acc2 = qb2[j];
  for(int k=0;k<256;k++) acc2 += h[k]*qw2[k*256+j];
  qv[b*256+j] = acc2;
}

// ---------------- K4: fused edge-GEMM + msg + gate + routing + scatter (32 rows / block)
__global__ __launch_bounds__(256,2) void k_edge_fused(
    const int* __restrict__ src, const int* __restrict__ rel, const int* __restrict__ tgt,
    const float* __restrict__ P,
    const float* __restrict__ ew2, const float* __restrict__ eb2,
    const float* __restrict__ mw1, const float* __restrict__ mb1,
    const float* __restrict__ mw2, const float* __restrict__ mb2,
    const float* __restrict__ gw1, const float* __restrict__ gb1,
    const float* __restrict__ gw2, const float* __restrict__ gb2,
    const float* __restrict__ gp, const float* __restrict__ sp,
    float* __restrict__ incoming)
{
  __shared__ float AT[256*32];   // k-major scratch: edge-hidden / gate-hidden / msg-hidden halves
  __shared__ float XT[256*32];   // Xe, k-major
  __shared__ float pv[32*32];    // proj values per row: [row][0..15]=g, [16..31]=s
  __shared__ float red[256];
  __shared__ float gatev[32];
  __shared__ int   nidx[32];

  int blk = blockIdx.x;
  int b   = blk >> 6;            // 64 blocks per batch (2048/32)
  int r0  = (blk & 63) * 32;
  int tid = threadIdx.x;
  int rr  = tid & 31;
  int kb  = (tid >> 5) * 32;

  // phase A: gather + gelu -> AT (k-major)
  {
    int gr = b*LL + r0 + rr;
    int s  = min(max(src[gr],0),49);
    int rl = rel[gr] & 1;
    int t  = min(max(tgt[gr],0),49);
    const float* ps = P + s*256;
    const float* pr = P + (50+rl)*256;
    const float* pt = P + (52+t)*256;
    #pragma unroll
    for(int j=0;j<32;j+=4){
      int k = kb + j;
      float4 vs = *(const float4*)(ps+k);
      float4 vr = *(const float4*)(pr+k);
      float4 vt = *(const float4*)(pt+k);
      AT[(k+0)*32+rr] = geluf(vs.x+vr.x+vt.x);
      AT[(k+1)*32+rr] = geluf(vs.y+vr.y+vt.y);
      AT[(k+2)*32+rr] = geluf(vs.z+vr.z+vt.z);
      AT[(k+3)*32+rr] = geluf(vs.w+vr.w+vt.w);
    }
  }
  __syncthreads();

  int c = tid;
  // phase B: Xe = AT^T @ ew2 + eb2 -> XT (k-major)
  {
    float acc[32];
    #pragma unroll
    for(int r=0;r<32;r++) acc[r]=0.f;
    float w = ew2[c];
    for(int k=0;k<256;k++){
      float wn = (k<255)? ew2[(k+1)*256+c] : 0.f;
      fma32(&AT[k*32], w, acc);
      w = wn;
    }
    float bb = eb2[c];
    #pragma unroll
    for(int r=0;r<32;r++) XT[c*32+r] = acc[r]+bb;
  }
  __syncthreads();

  // phase C: gate hidden = gelu(XT^T @ gw1 + gb1) -> AT
  {
    float acc[32];
    #pragma unroll
    for(int r=0;r<32;r++) acc[r]=0.f;
    float w = gw1[c];
    for(int k=0;k<256;k++){
      float wn = (k<255)? gw1[(k+1)*256+c] : 0.f;
      fma32(&XT[k*32], w, acc);
      w = wn;
    }
    float bb = gb1[c];
    #pragma unroll
    for(int r=0;r<32;r++) AT[c*32+r] = geluf(acc[r]+bb);
  }
  __syncthreads();

  // phase D: gate scalar + routing argmax
  {
    int r2 = tid>>3, g = tid&7;
    float s1 = 0.f;
    for(int k=g*32;k<g*32+32;k++) s1 += AT[k*32+r2]*gw2[k];
    red[r2*8+g] = s1;
    // proj: 4 columns per thread, cols 0..15 -> gproj, 16..31 -> sproj
    int c0 = g*4;
    const float* w0 = (c0+0<16)? gp+(c0+0) : sp+(c0+0-16);
    const float* w1 = (c0+1<16)? gp+(c0+1) : sp+(c0+1-16);
    const float* w2 = (c0+2<16)? gp+(c0+2) : sp+(c0+2-16);
    const float* w3 = (c0+3<16)? gp+(c0+3) : sp+(c0+3-16);
    float p0=0.f,p1=0.f,p2=0.f,p3=0.f;
    for(int k=0;k<256;k++){
      float x = XT[k*32+r2];
      p0 += x*w0[k*16]; p1 += x*w1[k*16];
      p2 += x*w2[k*16]; p3 += x*w3[k*16];
    }
    pv[r2*32+c0+0]=p0; pv[r2*32+c0+1]=p1; pv[r2*32+c0+2]=p2; pv[r2*32+c0+3]=p3;
    __syncthreads();
    if(tid < 32){
      float ssum = 0.f;
      for(int i=0;i<8;i++) ssum += red[tid*8+i];
      gatev[tid] = 1.f/(1.f+expf(-(ssum + gb2[0])));
      float bg = pv[tid*32+0]; int big = 0;
      for(int j=1;j<16;j++){ float x=pv[tid*32+j]; if(x>bg){bg=x;big=j;} }
      float bs = pv[tid*32+16]; int bis = 0;
      for(int j=1;j<16;j++){ float x=pv[tid*32+16+j]; if(x>bs){bs=x;bis=j;} }
      nidx[tid] = big*16 + bis;
    }
  }
  __syncthreads();

  // phase E: msg MLP in two hidden halves (hidden buffer = AT), accumulate msg output
  float macc[32];
  #pragma unroll
  for(int r=0;r<32;r++) macc[r]=0.f;
  for(int half=0; half<2; half++){
    // msg hidden half -> AT
    {
      float acc[32];
      #pragma unroll
      for(int r=0;r<32;r++) acc[r]=0.f;
      int hc = half*256 + c;
      float w = mw1[hc];
      for(int k=0;k<256;k++){
        float wn = (k<255)? mw1[(k+1)*512+hc] : 0.f;
        fma32(&XT[k*32], w, acc);
        w = wn;
      }
      float bb = mb1[hc];
      __syncthreads();   // previous consumer of AT done
      #pragma unroll
      for(int r=0;r<32;r++) AT[c*32+r] = geluf(acc[r]+bb);
    }
    __syncthreads();
    // msg out partial: k over this half
    {
      float w = mw2[(half*256)*256 + c];
      for(int k=0;k<256;k++){
        float wn = (k<255)? mw2[(half*256+k+1)*256+c] : 0.f;
        fma32(&AT[k*32], w, macc);
        w = wn;
      }
    }
    __syncthreads();
  }
  // phase F: scatter with gate
  {
    float bb = mb2[c];
    #pragma unroll
    for(int r=0;r<32;r++){
      float val = (macc[r]+bb)*gatev[r];
      atomicAdd(&incoming[((size_t)b*NNODE + nidx[r])*256 + c], val);
    }
  }
}

// ---------------- K5: the 64 q-rows through msg/gate/route/scatter
__global__ __launch_bounds__(256) void k_qrow(const float* __restrict__ qv,
    const float* __restrict__ mw1, const float* __restrict__ mb1,
    const float* __restrict__ mw2, const float* __restrict__ mb2,
    const float* __restrict__ gw1, const float* __restrict__ gb1,
    const float* __restrict__ gw2, const float* __restrict__ gb2,
    const float* __restrict__ gp, const float* __restrict__ sp,
    float* __restrict__ incoming){
  __shared__ float x[256];
  __shared__ float mh[512];
  __shared__ float gh[256];
  __shared__ float pv[32];
  __shared__ float rbuf[4];
  __shared__ float gv;
  __shared__ int nn;
  int b = blockIdx.x, j = threadIdx.x;
  x[j] = qv[b*256+j];
  __syncthreads();
  float a0 = mb1[j], a1 = mb1[256+j], g0 = gb1[j];
  for(int k=0;k<256;k++){
    float xv = x[k];
    a0 += xv*mw1[k*512+j];
    a1 += xv*mw1[k*512+256+j];
    g0 += xv*gw1[k*256+j];
  }
  mh[j] = geluf(a0); mh[256+j] = geluf(a1); gh[j] = geluf(g0);
  if(j < 32){
    float s1 = 0.f;
    const float* w = (j<16)? gp+j : sp+(j-16);
    for(int k=0;k<256;k++) s1 += x[k]*w[k*16];
    pv[j] = s1;
  }
  __syncthreads();
  float m0 = mb2[j];
  for(int k=0;k<512;k++) m0 += mh[k]*mw2[k*256+j];
  float part = gh[j]*gw2[j];
  for(int o=32;o>0;o>>=1) part += __shfl_down(part,o);
  if((j&63)==0) rbuf[j>>6] = part;
  __syncthreads();
  if(j==0){
    float s1 = rbuf[0]+rbuf[1]+rbuf[2]+rbuf[3];
    gv = 1.f/(1.f+expf(-(s1 + gb2[0])));
    float bg = pv[0]; int big = 0;
    for(int t2=1;t2<16;t2++){ if(pv[t2]>bg){bg=pv[t2];big=t2;} }
    float bs = pv[16]; int bis = 0;
    for(int t2=1;t2<16;t2++){ if(pv[16+t2]>bs){bs=pv[16+t2];bis=t2;} }
    nn = big*16 + bis;
  }
  __syncthreads();
  atomicAdd(&incoming[((size_t)b*NNODE + nn)*256 + j], m0*gv);
}

// ---------------- K6: Cpre = incoming @ upd_w1[256:512] + upd_b1   (rows=16384, K=256, C=512)
__global__ __launch_bounds__(256,2) void k_cpre(const float* __restrict__ incoming,
    const float* __restrict__ uw1, const float* __restrict__ ub1, float* __restrict__ Cpre){
  __shared__ float ATl[256*32];
  int blk = blockIdx.x, row0 = blk*32;
  int tid = threadIdx.x, rr = tid&31, kb = (tid>>5)*32;
  const float* ip = incoming + (size_t)(row0+rr)*256;
  #pragma unroll
  for(int j=0;j<32;j+=4){
    float4 v = *(const float4*)(ip+kb+j);
    ATl[(kb+j+0)*32+rr]=v.x; ATl[(kb+j+1)*32+rr]=v.y;
    ATl[(kb+j+2)*32+rr]=v.z; ATl[(kb+j+3)*32+rr]=v.w;
  }
  __syncthreads();
  float acc0[32], acc1[32];
  #pragma unroll
  for(int r=0;r<32;r++){acc0[r]=0.f;acc1[r]=0.f;}
  int c = tid;
  float w0 = uw1[256*512 + c], w1 = uw1[256*512 + 256 + c];
  for(int k=0;k<256;k++){
    float w0n = (k<255)? uw1[(257+k)*512 + c] : 0.f;
    float w1n = (k<255)? uw1[(257+k)*512 + 256 + c] : 0.f;
    fma32_2(&ATl[k*32], w0, w1, acc0, acc1);
    w0 = w0n; w1 = w1n;
  }
  float b0 = ub1[c], b1 = ub1[256+c];
  #pragma unroll
  for(int r=0;r<32;r++){
    size_t ro = (size_t)(row0+r)*512;
    Cpre[ro+c]     = acc0[r]+b0;
    Cpre[ro+256+c] = acc1[r]+b1;
  }
}

// ---------------- K7a: H = gelu(S @ upd_w1[0:256] + Cpre)
__global__ __launch_bounds__(256,2) void k_step1(const float* __restrict__ S,
    const float* __restrict__ uw1, const float* __restrict__ Cpre, float* __restrict__ H){
  __shared__ float ST[256*32];
  int blk = blockIdx.x, row0 = blk*32;
  int tid = threadIdx.x, rr = tid&31, kb = (tid>>5)*32;
  const float* sp_ = S + (size_t)(row0+rr)*256;
  #pragma unroll
  for(int j=0;j<32;j+=4){
    float4 v = *(const float4*)(sp_+kb+j);
    ST[(kb+j+0)*32+rr]=v.x; ST[(kb+j+1)*32+rr]=v.y;
    ST[(kb+j+2)*32+rr]=v.z; ST[(kb+j+3)*32+rr]=v.w;
  }
  __syncthreads();
  float acc0[32], acc1[32];
  #pragma unroll
  for(int r=0;r<32;r++){acc0[r]=0.f;acc1[r]=0.f;}
  int c = tid;
  float w0 = uw1[c], w1 = uw1[256+c];
  for(int k=0;k<256;k++){
    float w0n = (k<255)? uw1[(k+1)*512 + c] : 0.f;
    float w1n = (k<255)? uw1[(k+1)*512 + 256 + c] : 0.f;
    fma32_2(&ST[k*32], w0, w1, acc0, acc1);
    w0 = w0n; w1 = w1n;
  }
  #pragma unroll
  for(int r=0;r<32;r++){
    size_t ro = (size_t)(row0+r)*512;
    H[ro+c]     = geluf(acc0[r]+Cpre[ro+c]);
    H[ro+256+c] = geluf(acc1[r]+Cpre[ro+256+c]);
  }
}

// ---------------- K7b: u = H @ upd_w2 + b2 ; S = LN(S+u)*ln_w + ln_b
__global__ __launch_bounds__(256,2) void k_step2(const float* __restrict__ H,
    const float* __restrict__ uw2, const float* __restrict__ ub2,
    const float* __restrict__ lnw, const float* __restrict__ lnb, float* __restrict__ S){
  __shared__ float HT[512*32];
  __shared__ float red[512];
  __shared__ float mu[32], rs[32];
  int blk = blockIdx.x, row0 = blk*32;
  int tid = threadIdx.x, rr = tid&31, kb = (tid>>5)*64;
  const float* hp = H + (size_t)(row0+rr)*512;
  #pragma unroll
  for(int j=0;j<64;j+=4){
    float4 v = *(const float4*)(hp+kb+j);
    HT[(kb+j+0)*32+rr]=v.x; HT[(kb+j+1)*32+rr]=v.y;
    HT[(kb+j+2)*32+rr]=v.z; HT[(kb+j+3)*32+rr]=v.w;
  }
  __syncthreads();
  float acc[32];
  #pragma unroll
  for(int r=0;r<32;r++) acc[r]=0.f;
  int c = tid;
  float w = uw2[c];
  for(int k=0;k<512;k++){
    float wn = (k<511)? uw2[(k+1)*256+c] : 0.f;
    fma32(&HT[k*32], w, acc);
    w = wn;
  }
  float v[32]; float ub = ub2[c];
  #pragma unroll
  for(int r=0;r<32;r++) v[r] = S[(size_t)(row0+r)*256+c] + acc[r] + ub;
  __syncthreads();               // HT free
  float* V = HT;
  #pragma unroll
  for(int r=0;r<32;r++) V[r*256+c] = v[r];
  __syncthreads();
  int r2 = tid>>3, g = tid&7;
  float s1=0.f, s2=0.f;
  for(int j=g*32;j<g*32+32;j++){ float x=V[r2*256+j]; s1+=x; s2+=x*x; }
  red[r2*8+g] = s1; red[256+r2*8+g] = s2;
  __syncthreads();
  if(g==0){
    float ss=0.f, qq=0.f;
    for(int i=0;i<8;i++){ ss+=red[r2*8+i]; qq+=red[256+r2*8+i]; }
    float m = ss*(1.f/256.f);
    mu[r2] = m;
    rs[r2] = rsqrtf(qq*(1.f/256.f) - m*m + 1e-5f);
  }
  __syncthreads();
  float lw = lnw[c], lb = lnb[c];
  #pragma unroll
  for(int r=0;r<32;r++) S[(size_t)(row0+r)*256+c] = (v[r]-mu[r])*rs[r]*lw + lb;
}

// ---------------- init S from S_init broadcast
__global__ void k_sinit(const float* __restrict__ Sini, float* __restrict__ S){
  int total = NB*NNODE*256;
  for(int t = blockIdx.x*blockDim.x + threadIdx.x; t < total; t += gridDim.x*blockDim.x)
    S[t] = Sini[t & 65535];
}

// ---------------- head
__global__ __launch_bounds__(256) void k_head(const int* __restrict__ qsrc, const int* __restrict__ qtgt,
    const float* __restrict__ S, const float* __restrict__ hw1, const float* __restrict__ hb1,
    const float* __restrict__ hw2, const float* __restrict__ hb2, float* __restrict__ out){
  __shared__ float a[512];
  __shared__ float h[256];
  __shared__ float rbuf[8];
  int b = blockIdx.x, j = threadIdx.x;
  int s = min(max(qsrc[b],0),255), t = min(max(qtgt[b],0),255);
  a[j]     = S[((size_t)b*NNODE + s)*256 + j];
  a[256+j] = S[((size_t)b*NNODE + t)*256 + j];
  __syncthreads();
  float acc = hb1[j];
  for(int k=0;k<512;k++) acc += a[k]*hw1[k*256+j];
  h[j] = geluf(acc);
  __syncthreads();
  float p0 = h[j]*hw2[j*2], p1 = h[j]*hw2[j*2+1];
  for(int o=32;o>0;o>>=1){ p0 += __shfl_down(p0,o); p1 += __shfl_down(p1,o); }
  if((j&63)==0){ rbuf[(j>>6)*2] = p0; rbuf[(j>>6)*2+1] = p1; }
  __syncthreads();
  if(j==0){
    out[b*2+0] = rbuf[0]+rbuf[2]+rbuf[4]+rbuf[6] + hb2[0];
    out[b*2+1] = rbuf[1]+rbuf[3]+rbuf[5]+rbuf[7] + hb2[1];
  }
}

extern "C" void kernel_launch(void* const* d_in, const int* in_sizes, int n_in,
                              void* d_out, int out_size, void* d_ws, size_t ws_size,
                              hipStream_t stream){
  (void)in_sizes; (void)n_in; (void)out_size; (void)ws_size;
  const int*  src  = (const int*)d_in[0];
  const int*  rel  = (const int*)d_in[1];
  const int*  tgt  = (const int*)d_in[2];
  // d_in[3] mask: unused
  const int*  qsrc = (const int*)d_in[4];
  const int*  qtgt = (const int*)d_in[5];
  const float* ne  = (const float*)d_in[6];
  const float* re  = (const float*)d_in[7];
  const float* ew1 = (const float*)d_in[8];  const float* eb1 = (const float*)d_in[9];
  const float* ew2 = (const float*)d_in[10]; const float* eb2 = (const float*)d_in[11];
  const float* qw1 = (const float*)d_in[12]; const float* qb1 = (const float*)d_in[13];
  const float* qw2 = (const float*)d_in[14]; const float* qb2 = (const float*)d_in[15];
  const float* gp  = (const float*)d_in[16]; const float* sp  = (const float*)d_in[17];
  const float* mw1 = (const float*)d_in[18]; const float* mb1 = (const float*)d_in[19];
  const float* mw2 = (const float*)d_in[20]; const float* mb2 = (const float*)d_in[21];
  const float* gw1 = (const float*)d_in[22]; const float* gb1 = (const float*)d_in[23];
  const float* gw2 = (const float*)d_in[24]; const float* gb2 = (const float*)d_in[25];
  const float* uw1 = (const float*)d_in[26]; const float* ub1 = (const float*)d_in[27];
  const float* uw2 = (const float*)d_in[28]; const float* ub2 = (const float*)d_in[29];
  const float* lnw = (const float*)d_in[30]; const float* lnb = (const float*)d_in[31];
  const float* Sini= (const float*)d_in[32];
  const float* hw1 = (const float*)d_in[33]; const float* hb1 = (const float*)d_in[34];
  const float* hw2 = (const float*)d_in[35]; const float* hb2 = (const float*)d_in[36];

  float* ws = (float*)d_ws;
  float* P        = ws;                 //   26112
  float* qv       = ws + 26112;         //   16384
  float* incoming = ws + 42496;         // 4194304
  float* Cpre     = ws + 4236800;       // 8388608
  float* S        = ws + 12625408;      // 4194304
  float* H        = ws + 16819712;      // 8388608  -> total 25208320 floats (~96 MiB)
  float* out = (float*)d_out;

  hipMemsetAsync(incoming, 0, (size_t)4194304*4, stream);
  k_precompute<<<102,256,0,stream>>>(ne,re,ew1,eb1,P);
  k_query<<<64,256,0,stream>>>(qsrc,qtgt,ne,qw1,qb1,qw2,qb2,qv);
  k_edge_fused<<<4096,256,0,stream>>>(src,rel,tgt,P,ew2,eb2,mw1,mb1,mw2,mb2,gw1,gb1,gw2,gb2,gp,sp,incoming);
  k_qrow<<<64,256,0,stream>>>(qv,mw1,mb1,mw2,mb2,gw1,gb1,gw2,gb2,gp,sp,incoming);
  k_cpre<<<512,256,0,stream>>>(incoming,uw1,ub1,Cpre);
  k_sinit<<<4096,256,0,stream>>>(Sini,S);
  for(int st=0; st<NSTEPS; st++){
    k_step1<<<512,256,0,stream>>>(S,uw1,Cpre,H);
    k_step2<<<512,256,0,stream>>>(H,uw2,ub2,lnw,lnb,S);
  }
  k_head<<<64,256,0,stream>>>(qsrc,qtgt,S,hw1,hb1,hw2,hb2,out);
}

// Round 3
// 5989.816 us; speedup vs baseline: 1.4589x; 1.4589x over previous
//
#include <hip/hip_runtime.h>
#include <hip/hip_bf16.h>
#include <math.h>

#define NB     64
#define LL     2048
#define DD     256
#define NNODE  256     // G*K
#define NSTEPS 32

typedef __hip_bfloat16 bf16;
typedef __attribute__((ext_vector_type(8))) short bf16x8;
typedef __attribute__((ext_vector_type(4))) float f32x4;

__device__ __forceinline__ float geluf(float x){ return 0.5f*x*(1.0f+erff(x*0.70710678118654752440f)); }

// fma over 32 rows, LDS row base 8B-aligned (stride 34 floats)
__device__ __forceinline__ void fma32(const float* Arow, float w, float* acc){
  const float2* ap = (const float2*)Arow;
  #pragma unroll
  for(int i=0;i<16;i++){
    float2 a = ap[i];
    acc[i*2+0] += a.x*w; acc[i*2+1] += a.y*w;
  }
}
// float4 version for stride-32 buffers (k_cpre)
__device__ __forceinline__ void fma32_2q(const float* Arow, float w0, float w1, float* acc0, float* acc1){
  const float4* ap = (const float4*)Arow;
  #pragma unroll
  for(int i=0;i<8;i++){
    float4 a = ap[i];
    acc0[i*4+0] += a.x*w0; acc0[i*4+1] += a.y*w0;
    acc0[i*4+2] += a.z*w0; acc0[i*4+3] += a.w*w0;
    acc1[i*4+0] += a.x*w1; acc1[i*4+1] += a.y*w1;
    acc1[i*4+2] += a.z*w1; acc1[i*4+3] += a.w*w1;
  }
}

// ---------------- K1: P tables: rows 0..49 src-part, 50..51 rel-part(+eb1), 52..101 tgt-part
__global__ __launch_bounds__(256) void k_precompute(const float* __restrict__ ne,
    const float* __restrict__ re, const float* __restrict__ ew1, const float* __restrict__ eb1,
    float* __restrict__ P){
  __shared__ float a[256];
  int row = blockIdx.x, j = threadIdx.x;
  const float* vec; const float* W;
  if(row < 50){ vec = ne + row*256; W = ew1; }
  else if(row < 52){ vec = re + (row-50)*256; W = ew1 + 256*256; }
  else { vec = ne + (row-52)*256; W = ew1 + 512*256; }
  a[j] = vec[j];
  __syncthreads();
  float acc = 0.f;
  for(int k=0;k<256;k++) acc += a[k]*W[k*256 + j];
  if(row >= 50 && row < 52) acc += eb1[j];
  P[row*256 + j] = acc;
}

// ---------------- K2: q[b] = MLP2(concat(ne[qsrc], ne[qtgt]))
__global__ __launch_bounds__(256) void k_query(const int* __restrict__ qsrc, const int* __restrict__ qtgt,
    const float* __restrict__ ne, const float* __restrict__ qw1, const float* __restrict__ qb1,
    const float* __restrict__ qw2, const float* __restrict__ qb2, float* __restrict__ qv){
  __shared__ float a[512];
  __shared__ float h[256];
  int b = blockIdx.x, j = threadIdx.x;
  int s = min(max(qsrc[b],0),49), t = min(max(qtgt[b],0),49);
  a[j]     = ne[s*256 + j];
  a[256+j] = ne[t*256 + j];
  __syncthreads();
  float acc = qb1[j];
  for(int k=0;k<512;k++) acc += a[k]*qw1[k*256+j];
  h[j] = geluf(acc);
  __syncthreads();
  float acc2 = qb2[j];
  for(int k=0;k<256;k++) acc2 += h[k]*qw2[k*256+j];
  qv[b*256+j] = acc2;
}

// ---------------- K4: fused edge-GEMM + msg + gate + routing + scatter (32 rows / block)
// LDS stride 34: transposed column writes go from 64-way to 4-way bank conflicts.
#define EST 34
__global__ __launch_bounds__(256,2) void k_edge_fused(
    const int* __restrict__ src, const int* __restrict__ rel, const int* __restrict__ tgt,
    const float* __restrict__ P,
    const float* __restrict__ ew2, const float* __restrict__ eb2,
    const float* __restrict__ mw1, const float* __restrict__ mb1,
    const float* __restrict__ mw2, const float* __restrict__ mb2,
    const float* __restrict__ gw1, const float* __restrict__ gb1,
    const float* __restrict__ gw2, const float* __restrict__ gb2,
    const float* __restrict__ gp, const float* __restrict__ sp,
    float* __restrict__ incoming)
{
  __shared__ float AT[256*EST];
  __shared__ float XT[256*EST];
  __shared__ float pv[32*32];
  __shared__ float red[256];
  __shared__ float gatev[32];
  __shared__ int   nidx[32];

  int blk = blockIdx.x;
  int b   = blk >> 6;
  int r0  = (blk & 63) * 32;
  int tid = threadIdx.x;
  int rr  = tid & 31;
  int kb  = (tid >> 5) * 32;

  // phase A: gather + gelu -> AT (k-major)
  {
    int gr = b*LL + r0 + rr;
    int s  = min(max(src[gr],0),49);
    int rl = rel[gr] & 1;
    int t  = min(max(tgt[gr],0),49);
    const float* ps = P + s*256;
    const float* pr = P + (50+rl)*256;
    const float* pt = P + (52+t)*256;
    #pragma unroll
    for(int j=0;j<32;j+=4){
      int k = kb + j;
      float4 vs = *(const float4*)(ps+k);
      float4 vr = *(const float4*)(pr+k);
      float4 vt = *(const float4*)(pt+k);
      AT[(k+0)*EST+rr] = geluf(vs.x+vr.x+vt.x);
      AT[(k+1)*EST+rr] = geluf(vs.y+vr.y+vt.y);
      AT[(k+2)*EST+rr] = geluf(vs.z+vr.z+vt.z);
      AT[(k+3)*EST+rr] = geluf(vs.w+vr.w+vt.w);
    }
  }
  __syncthreads();

  int c = tid;
  // phase B: Xe = AT^T @ ew2 + eb2 -> XT (k-major)
  {
    float acc[32];
    #pragma unroll
    for(int r=0;r<32;r++) acc[r]=0.f;
    for(int k8=0;k8<256;k8+=8){
      float wb[8];
      #pragma unroll
      for(int j=0;j<8;j++) wb[j] = ew2[(k8+j)*256+c];
      #pragma unroll
      for(int j=0;j<8;j++) fma32(&AT[(k8+j)*EST], wb[j], acc);
    }
    float bb = eb2[c];
    #pragma unroll
    for(int r=0;r<32;r++) XT[c*EST+r] = acc[r]+bb;
  }
  __syncthreads();

  // phase C: gate hidden = gelu(XT^T @ gw1 + gb1) -> AT
  {
    float acc[32];
    #pragma unroll
    for(int r=0;r<32;r++) acc[r]=0.f;
    for(int k8=0;k8<256;k8+=8){
      float wb[8];
      #pragma unroll
      for(int j=0;j<8;j++) wb[j] = gw1[(k8+j)*256+c];
      #pragma unroll
      for(int j=0;j<8;j++) fma32(&XT[(k8+j)*EST], wb[j], acc);
    }
    float bb = gb1[c];
    #pragma unroll
    for(int r=0;r<32;r++) AT[c*EST+r] = geluf(acc[r]+bb);
  }
  __syncthreads();

  // phase D: gate scalar + routing argmax (fp32 — decisions must match reference)
  {
    int r2 = tid>>3, g = tid&7;
    float s1 = 0.f;
    for(int k=g*32;k<g*32+32;k++) s1 += AT[k*EST+r2]*gw2[k];
    red[r2*8+g] = s1;
    int c0 = g*4;
    const float* w0 = (c0+0<16)? gp+(c0+0) : sp+(c0+0-16);
    const float* w1 = (c0+1<16)? gp+(c0+1) : sp+(c0+1-16);
    const float* w2 = (c0+2<16)? gp+(c0+2) : sp+(c0+2-16);
    const float* w3 = (c0+3<16)? gp+(c0+3) : sp+(c0+3-16);
    float p0=0.f,p1=0.f,p2=0.f,p3=0.f;
    for(int k=0;k<256;k++){
      float x = XT[k*EST+r2];
      p0 += x*w0[k*16]; p1 += x*w1[k*16];
      p2 += x*w2[k*16]; p3 += x*w3[k*16];
    }
    pv[r2*32+c0+0]=p0; pv[r2*32+c0+1]=p1; pv[r2*32+c0+2]=p2; pv[r2*32+c0+3]=p3;
    __syncthreads();
    if(tid < 32){
      float ssum = 0.f;
      for(int i=0;i<8;i++) ssum += red[tid*8+i];
      gatev[tid] = 1.f/(1.f+expf(-(ssum + gb2[0])));
      float bg = pv[tid*32+0]; int big = 0;
      for(int j=1;j<16;j++){ float x=pv[tid*32+j]; if(x>bg){bg=x;big=j;} }
      float bs = pv[tid*32+16]; int bis = 0;
      for(int j=1;j<16;j++){ float x=pv[tid*32+16+j]; if(x>bs){bs=x;bis=j;} }
      nidx[tid] = big*16 + bis;
    }
  }
  __syncthreads();

  // phase E: msg MLP in two hidden halves
  float macc[32];
  #pragma unroll
  for(int r=0;r<32;r++) macc[r]=0.f;
  for(int half=0; half<2; half++){
    {
      float acc[32];
      #pragma unroll
      for(int r=0;r<32;r++) acc[r]=0.f;
      int hc = half*256 + c;
      for(int k8=0;k8<256;k8+=8){
        float wb[8];
        #pragma unroll
        for(int j=0;j<8;j++) wb[j] = mw1[(k8+j)*512+hc];
        #pragma unroll
        for(int j=0;j<8;j++) fma32(&XT[(k8+j)*EST], wb[j], acc);
      }
      float bb = mb1[hc];
      __syncthreads();
      #pragma unroll
      for(int r=0;r<32;r++) AT[c*EST+r] = geluf(acc[r]+bb);
    }
    __syncthreads();
    {
      for(int k8=0;k8<256;k8+=8){
        float wb[8];
        #pragma unroll
        for(int j=0;j<8;j++) wb[j] = mw2[(half*256+k8+j)*256+c];
        #pragma unroll
        for(int j=0;j<8;j++) fma32(&AT[(k8+j)*EST], wb[j], macc);
      }
    }
    __syncthreads();
  }
  // phase F: scatter with gate
  {
    float bb = mb2[c];
    #pragma unroll
    for(int r=0;r<32;r++){
      float val = (macc[r]+bb)*gatev[r];
      atomicAdd(&incoming[((size_t)b*NNODE + nidx[r])*256 + c], val);
    }
  }
}

// ---------------- K5: the 64 q-rows through msg/gate/route/scatter
__global__ __launch_bounds__(256) void k_qrow(const float* __restrict__ qv,
    const float* __restrict__ mw1, const float* __restrict__ mb1,
    const float* __restrict__ mw2, const float* __restrict__ mb2,
    const float* __restrict__ gw1, const float* __restrict__ gb1,
    const float* __restrict__ gw2, const float* __restrict__ gb2,
    const float* __restrict__ gp, const float* __restrict__ sp,
    float* __restrict__ incoming){
  __shared__ float x[256];
  __shared__ float mh[512];
  __shared__ float gh[256];
  __shared__ float pv[32];
  __shared__ float rbuf[4];
  __shared__ float gv;
  __shared__ int nn;
  int b = blockIdx.x, j = threadIdx.x;
  x[j] = qv[b*256+j];
  __syncthreads();
  float a0 = mb1[j], a1 = mb1[256+j], g0 = gb1[j];
  for(int k=0;k<256;k++){
    float xv = x[k];
    a0 += xv*mw1[k*512+j];
    a1 += xv*mw1[k*512+256+j];
    g0 += xv*gw1[k*256+j];
  }
  mh[j] = geluf(a0); mh[256+j] = geluf(a1); gh[j] = geluf(g0);
  if(j < 32){
    float s1 = 0.f;
    const float* w = (j<16)? gp+j : sp+(j-16);
    for(int k=0;k<256;k++) s1 += x[k]*w[k*16];
    pv[j] = s1;
  }
  __syncthreads();
  float m0 = mb2[j];
  for(int k=0;k<512;k++) m0 += mh[k]*mw2[k*256+j];
  float part = gh[j]*gw2[j];
  for(int o=32;o>0;o>>=1) part += __shfl_down(part,o);
  if((j&63)==0) rbuf[j>>6] = part;
  __syncthreads();
  if(j==0){
    float s1 = rbuf[0]+rbuf[1]+rbuf[2]+rbuf[3];
    gv = 1.f/(1.f+expf(-(s1 + gb2[0])));
    float bg = pv[0]; int big = 0;
    for(int t2=1;t2<16;t2++){ if(pv[t2]>bg){bg=pv[t2];big=t2;} }
    float bs = pv[16]; int bis = 0;
    for(int t2=1;t2<16;t2++){ if(pv[16+t2]>bs){bs=pv[16+t2];bis=t2;} }
    nn = big*16 + bis;
  }
  __syncthreads();
  atomicAdd(&incoming[((size_t)b*NNODE + nn)*256 + j], m0*gv);
}

// ---------------- K6: Cpre = incoming @ upd_w1[256:512] + upd_b1   (fp32, loop-invariant)
__global__ __launch_bounds__(256,2) void k_cpre(const float* __restrict__ incoming,
    const float* __restrict__ uw1, const float* __restrict__ ub1, float* __restrict__ Cpre){
  __shared__ float ATl[256*32];
  int blk = blockIdx.x, row0 = blk*32;
  int tid = threadIdx.x, rr = tid&31, kb = (tid>>5)*32;
  const float* ip = incoming + (size_t)(row0+rr)*256;
  #pragma unroll
  for(int j=0;j<32;j+=4){
    float4 v = *(const float4*)(ip+kb+j);
    ATl[(kb+j+0)*32+rr]=v.x; ATl[(kb+j+1)*32+rr]=v.y;
    ATl[(kb+j+2)*32+rr]=v.z; ATl[(kb+j+3)*32+rr]=v.w;
  }
  __syncthreads();
  float acc0[32], acc1[32];
  #pragma unroll
  for(int r=0;r<32;r++){acc0[r]=0.f;acc1[r]=0.f;}
  int c = tid;
  float w0 = uw1[256*512 + c], w1 = uw1[256*512 + 256 + c];
  for(int k=0;k<256;k++){
    float w0n = (k<255)? uw1[(257+k)*512 + c] : 0.f;
    float w1n = (k<255)? uw1[(257+k)*512 + 256 + c] : 0.f;
    fma32_2q(&ATl[k*32], w0, w1, acc0, acc1);
    w0 = w0n; w1 = w1n;
  }
  float b0 = ub1[c], b1 = ub1[256+c];
  #pragma unroll
  for(int r=0;r<32;r++){
    size_t ro = (size_t)(row0+r)*512;
    Cpre[ro+c]     = acc0[r]+b0;
    Cpre[ro+256+c] = acc1[r]+b1;
  }
}

// ---------------- weight prep: transpose to [n][k] bf16 for MFMA B-fragments
__global__ __launch_bounds__(256) void k_wprep(const float* __restrict__ uw1,
    const float* __restrict__ uw2, bf16* __restrict__ WTa, bf16* __restrict__ WT2){
  int i = blockIdx.x*256 + threadIdx.x;   // 0 .. 131071
  {  // WTa[n][k] = uw1[k][n], k<256, n<512
    int n = i >> 8, k = i & 255;
    WTa[i] = __float2bfloat16(uw1[k*512 + n]);
  }
  {  // WT2[n][k] = uw2[k][n], k<512, n<256
    int n = i >> 9, k = i & 511;
    WT2[i] = __float2bfloat16(uw2[k*256 + n]);
  }
}

// ---------------- persistent 32-step update: MFMA bf16, fp32 state/LN
#define SROW 264   // bf16 elems; 528 B row stride (16B-aligned)
#define HROW 520   // bf16 elems; 1040 B row stride (16B-aligned)
__global__ __launch_bounds__(256,2) void k_steps(
    const float* __restrict__ Sini, const float* __restrict__ Cpre,
    const bf16* __restrict__ WTa, const bf16* __restrict__ WT2,
    const float* __restrict__ ub2, const float* __restrict__ lnw,
    const float* __restrict__ lnb, float* __restrict__ Sout)
{
  __shared__ __align__(16) bf16 Sbf[32*SROW];
  __shared__ __align__(16) bf16 Hbf[32*HROW];
  __shared__ float redA[32*4], redB[32*4];

  int tid = threadIdx.x;
  int w   = tid >> 6;
  int lane= tid & 63;
  int l15 = lane & 15;
  int l4  = lane >> 4;     // 0..3
  int row0 = blockIdx.x * 32;

  // C-fragment ownership: rows r = mt*16 + l4*4 + reg ; cols (GEMM2/N=256 view) col = w*64 + nt*16 + l15
  f32x4 Sreg[2][4];
  float ub[4], lw[4], lb[4];
  #pragma unroll
  for(int nt=0;nt<4;nt++){
    int col = w*64 + nt*16 + l15;
    ub[nt] = ub2[col]; lw[nt] = lnw[col]; lb[nt] = lnb[col];
  }
  #pragma unroll
  for(int mt=0;mt<2;mt++)
  #pragma unroll
  for(int nt=0;nt<4;nt++){
    int col = w*64 + nt*16 + l15;
    #pragma unroll
    for(int reg=0;reg<4;reg++){
      int r = mt*16 + l4*4 + reg;
      int node = (row0 + r) & 255;
      float v = Sini[node*256 + col];
      Sreg[mt][nt][reg] = v;
      Sbf[r*SROW + col] = __float2bfloat16(v);
    }
  }
  __syncthreads();

  const float* CpreBlk = Cpre + (size_t)row0*512;

  for(int step=0; step<NSTEPS; step++){
    // ---- GEMM1: H(32x512) = gelu(Sbf(32x256) @ W1a + Cpre) ; wave handles 128 cols
    f32x4 acc1[2][8];
    #pragma unroll
    for(int mt=0;mt<2;mt++)
    #pragma unroll
    for(int nt=0;nt<8;nt++) acc1[mt][nt] = (f32x4){0.f,0.f,0.f,0.f};
    for(int kc=0;kc<8;kc++){
      int k0 = kc*32 + l4*8;
      bf16x8 a0 = *(const bf16x8*)&Sbf[(     l15)*SROW + k0];
      bf16x8 a1 = *(const bf16x8*)&Sbf[(16 + l15)*SROW + k0];
      #pragma unroll
      for(int nt=0;nt<8;nt++){
        int n = w*128 + nt*16 + l15;
        bf16x8 bfr = *(const bf16x8*)&WTa[n*256 + k0];
        acc1[0][nt] = __builtin_amdgcn_mfma_f32_16x16x32_bf16(a0, bfr, acc1[0][nt], 0,0,0);
        acc1[1][nt] = __builtin_amdgcn_mfma_f32_16x16x32_bf16(a1, bfr, acc1[1][nt], 0,0,0);
      }
    }
    #pragma unroll
    for(int mt=0;mt<2;mt++)
    #pragma unroll
    for(int nt=0;nt<8;nt++){
      int n = w*128 + nt*16 + l15;
      #pragma unroll
      for(int reg=0;reg<4;reg++){
        int r = mt*16 + l4*4 + reg;
        float h = geluf(acc1[mt][nt][reg] + CpreBlk[(size_t)r*512 + n]);
        Hbf[r*HROW + n] = __float2bfloat16(h);
      }
    }
    __syncthreads();   // Hbf ready (and Sbf reads done)

    // ---- GEMM2: u(32x256) = Hbf(32x512) @ W2 ; wave handles 64 cols
    f32x4 acc2[2][4];
    #pragma unroll
    for(int mt=0;mt<2;mt++)
    #pragma unroll
    for(int nt=0;nt<4;nt++) acc2[mt][nt] = (f32x4){0.f,0.f,0.f,0.f};
    for(int kc=0;kc<16;kc++){
      int k0 = kc*32 + l4*8;
      bf16x8 a0 = *(const bf16x8*)&Hbf[(     l15)*HROW + k0];
      bf16x8 a1 = *(const bf16x8*)&Hbf[(16 + l15)*HROW + k0];
      #pragma unroll
      for(int nt=0;nt<4;nt++){
        int n = w*64 + nt*16 + l15;
        bf16x8 bfr = *(const bf16x8*)&WT2[n*512 + k0];
        acc2[0][nt] = __builtin_amdgcn_mfma_f32_16x16x32_bf16(a0, bfr, acc2[0][nt], 0,0,0);
        acc2[1][nt] = __builtin_amdgcn_mfma_f32_16x16x32_bf16(a1, bfr, acc2[1][nt], 0,0,0);
      }
    }
    // ---- residual + LN (fp32)
    #pragma unroll
    for(int mt=0;mt<2;mt++)
    #pragma unroll
    for(int nt=0;nt<4;nt++)
    #pragma unroll
    for(int reg=0;reg<4;reg++)
      acc2[mt][nt][reg] = Sreg[mt][nt][reg] + acc2[mt][nt][reg] + ub[nt];

    #pragma unroll
    for(int mt=0;mt<2;mt++)
    #pragma unroll
    for(int reg=0;reg<4;reg++){
      float s1 = 0.f, s2 = 0.f;
      #pragma unroll
      for(int nt=0;nt<4;nt++){ float v = acc2[mt][nt][reg]; s1 += v; s2 += v*v; }
      #pragma unroll
      for(int o=1;o<16;o<<=1){ s1 += __shfl_xor(s1,o); s2 += __shfl_xor(s2,o); }
      if(l15 == 0){
        int r = mt*16 + l4*4 + reg;
        redA[r*4+w] = s1; redB[r*4+w] = s2;
      }
    }
    __syncthreads();   // red ready (and Hbf reads done)

    #pragma unroll
    for(int mt=0;mt<2;mt++)
    #pragma unroll
    for(int reg=0;reg<4;reg++){
      int r = mt*16 + l4*4 + reg;
      float ss = redA[r*4+0]+redA[r*4+1]+redA[r*4+2]+redA[r*4+3];
      float qq = redB[r*4+0]+redB[r*4+1]+redB[r*4+2]+redB[r*4+3];
      float mu = ss*(1.f/256.f);
      float rs = rsqrtf(qq*(1.f/256.f) - mu*mu + 1e-5f);
      #pragma unroll
      for(int nt=0;nt<4;nt++){
        int col = w*64 + nt*16 + l15;
        float sv = (acc2[mt][nt][reg]-mu)*rs*lw[nt] + lb[nt];
        Sreg[mt][nt][reg] = sv;
        Sbf[r*SROW + col] = __float2bfloat16(sv);
      }
    }
    __syncthreads();   // Sbf ready for next step (and red reusable)
  }

  // write final S (fp32) for the head
  #pragma unroll
  for(int mt=0;mt<2;mt++)
  #pragma unroll
  for(int nt=0;nt<4;nt++){
    int col = w*64 + nt*16 + l15;
    #pragma unroll
    for(int reg=0;reg<4;reg++){
      int r = mt*16 + l4*4 + reg;
      Sout[(size_t)(row0+r)*256 + col] = Sreg[mt][nt][reg];
    }
  }
}

// ---------------- head
__global__ __launch_bounds__(256) void k_head(const int* __restrict__ qsrc, const int* __restrict__ qtgt,
    const float* __restrict__ S, const float* __restrict__ hw1, const float* __restrict__ hb1,
    const float* __restrict__ hw2, const float* __restrict__ hb2, float* __restrict__ out){
  __shared__ float a[512];
  __shared__ float h[256];
  __shared__ float rbuf[8];
  int b = blockIdx.x, j = threadIdx.x;
  int s = min(max(qsrc[b],0),255), t = min(max(qtgt[b],0),255);
  a[j]     = S[((size_t)b*NNODE + s)*256 + j];
  a[256+j] = S[((size_t)b*NNODE + t)*256 + j];
  __syncthreads();
  float acc = hb1[j];
  for(int k=0;k<512;k++) acc += a[k]*hw1[k*256+j];
  h[j] = geluf(acc);
  __syncthreads();
  float p0 = h[j]*hw2[j*2], p1 = h[j]*hw2[j*2+1];
  for(int o=32;o>0;o>>=1){ p0 += __shfl_down(p0,o); p1 += __shfl_down(p1,o); }
  if((j&63)==0){ rbuf[(j>>6)*2] = p0; rbuf[(j>>6)*2+1] = p1; }
  __syncthreads();
  if(j==0){
    out[b*2+0] = rbuf[0]+rbuf[2]+rbuf[4]+rbuf[6] + hb2[0];
    out[b*2+1] = rbuf[1]+rbuf[3]+rbuf[5]+rbuf[7] + hb2[1];
  }
}

extern "C" void kernel_launch(void* const* d_in, const int* in_sizes, int n_in,
                              void* d_out, int out_size, void* d_ws, size_t ws_size,
                              hipStream_t stream){
  (void)in_sizes; (void)n_in; (void)out_size; (void)ws_size;
  const int*  src  = (const int*)d_in[0];
  const int*  rel  = (const int*)d_in[1];
  const int*  tgt  = (const int*)d_in[2];
  const int*  qsrc = (const int*)d_in[4];
  const int*  qtgt = (const int*)d_in[5];
  const float* ne  = (const float*)d_in[6];
  const float* re  = (const float*)d_in[7];
  const float* ew1 = (const float*)d_in[8];  const float* eb1 = (const float*)d_in[9];
  const float* ew2 = (const float*)d_in[10]; const float* eb2 = (const float*)d_in[11];
  const float* qw1 = (const float*)d_in[12]; const float* qb1 = (const float*)d_in[13];
  const float* qw2 = (const float*)d_in[14]; const float* qb2 = (const float*)d_in[15];
  const float* gp  = (const float*)d_in[16]; const float* sp  = (const float*)d_in[17];
  const float* mw1 = (const float*)d_in[18]; const float* mb1 = (const float*)d_in[19];
  const float* mw2 = (const float*)d_in[20]; const float* mb2 = (const float*)d_in[21];
  const float* gw1 = (const float*)d_in[22]; const float* gb1 = (const float*)d_in[23];
  const float* gw2 = (const float*)d_in[24]; const float* gb2 = (const float*)d_in[25];
  const float* uw1 = (const float*)d_in[26]; const float* ub1 = (const float*)d_in[27];
  const float* uw2 = (const float*)d_in[28]; const float* ub2 = (const float*)d_in[29];
  const float* lnw = (const float*)d_in[30]; const float* lnb = (const float*)d_in[31];
  const float* Sini= (const float*)d_in[32];
  const float* hw1 = (const float*)d_in[33]; const float* hb1 = (const float*)d_in[34];
  const float* hw2 = (const float*)d_in[35]; const float* hb2 = (const float*)d_in[36];

  float* ws = (float*)d_ws;
  float* P        = ws;                  //    26112
  float* qv       = ws + 26112;          //    16384
  float* incoming = ws + 42496;          //  4194304
  float* Cpre     = ws + 4236800;        //  8388608
  float* Sout     = ws + 12625408;       //  4194304
  bf16*  WTa      = (bf16*)(ws + 16819712);  // 131072 bf16 (65536 f32-slots)
  bf16*  WT2      = (bf16*)(ws + 16885248);  // 131072 bf16
  float* out = (float*)d_out;

  hipMemsetAsync(incoming, 0, (size_t)4194304*4, stream);
  k_wprep<<<512,256,0,stream>>>(uw1,uw2,WTa,WT2);
  k_precompute<<<102,256,0,stream>>>(ne,re,ew1,eb1,P);
  k_query<<<64,256,0,stream>>>(qsrc,qtgt,ne,qw1,qb1,qw2,qb2,qv);
  k_edge_fused<<<4096,256,0,stream>>>(src,rel,tgt,P,ew2,eb2,mw1,mb1,mw2,mb2,gw1,gb1,gw2,gb2,gp,sp,incoming);
  k_qrow<<<64,256,0,stream>>>(qv,mw1,mb1,mw2,mb2,gw1,gb1,gw2,gb2,gp,sp,incoming);
  k_cpre<<<512,256,0,stream>>>(incoming,uw1,ub1,Cpre);
  k_steps<<<512,256,0,stream>>>(Sini,Cpre,WTa,WT2,ub2,lnw,lnb,Sout);
  k_head<<<64,256,0,stream>>>(qsrc,qtgt,Sout,hw1,hb1,hw2,hb2,out);
}

// Round 4
// 3505.901 us; speedup vs baseline: 2.4925x; 1.7085x over previous
//
#include <hip/hip_runtime.h>
#include <hip/hip_bf16.h>
#include <math.h>

#define NB     64
#define LL     2048
#define DD     256
#define NNODE  256     // G*K
#define NSTEPS 32

typedef __hip_bfloat16 bf16;
typedef __attribute__((ext_vector_type(8))) short bf16x8;
typedef __attribute__((ext_vector_type(4))) float f32x4;

__device__ __forceinline__ float geluf(float x){ return 0.5f*x*(1.0f+erff(x*0.70710678118654752440f)); }
__device__ __forceinline__ short f2bs(float x){ bf16 h = __float2bfloat16(x); return __builtin_bit_cast(short, h); }
__device__ __forceinline__ float bs2f(short s){ bf16 h = __builtin_bit_cast(bf16, s); return __bfloat162float(h); }

// build bf16 hi/lo split fragment from 8 fp32 values
__device__ __forceinline__ void split8(float4 a, float4 b, bf16x8& hi, bf16x8& lo){
  float av[8] = {a.x,a.y,a.z,a.w,b.x,b.y,b.z,b.w};
  #pragma unroll
  for(int j=0;j<8;j++){
    short h = f2bs(av[j]);
    hi[j] = h;
    lo[j] = f2bs(av[j] - bs2f(h));
  }
}
__device__ __forceinline__ bf16x8 cvt8(float4 a, float4 b){
  float av[8] = {a.x,a.y,a.z,a.w,b.x,b.y,b.z,b.w};
  bf16x8 v;
  #pragma unroll
  for(int j=0;j<8;j++) v[j] = f2bs(av[j]);
  return v;
}

// ---------------- K1: P tables: rows 0..49 src-part, 50..51 rel-part(+eb1), 52..101 tgt-part
__global__ __launch_bounds__(256) void k_precompute(const float* __restrict__ ne,
    const float* __restrict__ re, const float* __restrict__ ew1, const float* __restrict__ eb1,
    float* __restrict__ P){
  __shared__ float a[256];
  int row = blockIdx.x, j = threadIdx.x;
  const float* vec; const float* W;
  if(row < 50){ vec = ne + row*256; W = ew1; }
  else if(row < 52){ vec = re + (row-50)*256; W = ew1 + 256*256; }
  else { vec = ne + (row-52)*256; W = ew1 + 512*256; }
  a[j] = vec[j];
  __syncthreads();
  float acc = 0.f;
  for(int k=0;k<256;k++) acc += a[k]*W[k*256 + j];
  if(row >= 50 && row < 52) acc += eb1[j];
  P[row*256 + j] = acc;
}

// ---------------- K2: q[b] = MLP2(concat(ne[qsrc], ne[qtgt]))
__global__ __launch_bounds__(256) void k_query(const int* __restrict__ qsrc, const int* __restrict__ qtgt,
    const float* __restrict__ ne, const float* __restrict__ qw1, const float* __restrict__ qb1,
    const float* __restrict__ qw2, const float* __restrict__ qb2, float* __restrict__ qv){
  __shared__ float a[512];
  __shared__ float h[256];
  int b = blockIdx.x, j = threadIdx.x;
  int s = min(max(qsrc[b],0),49), t = min(max(qtgt[b],0),49);
  a[j]     = ne[s*256 + j];
  a[256+j] = ne[t*256 + j];
  __syncthreads();
  float acc = qb1[j];
  for(int k=0;k<512;k++) acc += a[k]*qw1[k*256+j];
  h[j] = geluf(acc);
  __syncthreads();
  float acc2 = qb2[j];
  for(int k=0;k<256;k++) acc2 += h[k]*qw2[k*256+j];
  qv[b*256+j] = acc2;
}

// ---------------- weight prep: all transposed [n][k] bf16 (hi, and hi/lo for ew2)
__global__ __launch_bounds__(256) void k_wprep(
    const float* __restrict__ uw1, const float* __restrict__ uw2,
    const float* __restrict__ ew2, const float* __restrict__ gw1,
    const float* __restrict__ mw1, const float* __restrict__ mw2,
    bf16* __restrict__ WTa, bf16* __restrict__ WT2,
    bf16* __restrict__ Weh, bf16* __restrict__ Wel, bf16* __restrict__ Wg,
    bf16* __restrict__ Wm1, bf16* __restrict__ Wm2){
  int i = blockIdx.x*256 + threadIdx.x;   // 0 .. 131071
  { int n = i >> 8, k = i & 255;  WTa[i] = __float2bfloat16(uw1[k*512 + n]); }
  { int n = i >> 9, k = i & 511;  WT2[i] = __float2bfloat16(uw2[k*256 + n]); }
  { int n = i >> 8, k = i & 255;  Wm1[i] = __float2bfloat16(mw1[k*512 + n]); }
  { int n = i >> 9, k = i & 511;  Wm2[i] = __float2bfloat16(mw2[k*256 + n]); }
  if(i < 65536){
    int n = i >> 8, k = i & 255;
    float v = ew2[k*256 + n];
    bf16 h = __float2bfloat16(v);
    Weh[i] = h;
    Wel[i] = __float2bfloat16(v - __bfloat162float(h));
    Wg[i]  = __float2bfloat16(gw1[k*256 + n]);
  }
}

// ---------------- K4: MFMA edge pipeline: gather->edge GEMM(split)->gate/route->msg->scatter
#define AST 260   // fp32 LDS row stride (1040B: 16B-aligned, bank-balanced)
#define MST 520   // bf16 LDS row stride (1040B)
__global__ __launch_bounds__(256,2) void k_edge_mfma(
    const int* __restrict__ src, const int* __restrict__ rel, const int* __restrict__ tgt,
    const float* __restrict__ P,
    const bf16* __restrict__ Weh, const bf16* __restrict__ Wel, const float* __restrict__ eb2,
    const bf16* __restrict__ Wg, const float* __restrict__ gb1,
    const float* __restrict__ gw2, const float* __restrict__ gb2,
    const float* __restrict__ gp, const float* __restrict__ sp,
    const bf16* __restrict__ Wm1, const float* __restrict__ mb1,
    const bf16* __restrict__ Wm2, const float* __restrict__ mb2,
    float* __restrict__ incoming)
{
  __shared__ __align__(16) float Af[32*AST];   // fp32 gelu'd edge-hidden; overlaid by Mh (bf16) from E1 on
  __shared__ __align__(16) float Xf[32*AST];   // fp32 Xe
  __shared__ float pv[32*32];
  __shared__ float redG[32*4];
  __shared__ float gatev[32];
  __shared__ int   nidx[32];
  bf16* Mh = (bf16*)Af;    // 32*520*2 B == 32*260*4 B exactly

  int tid = threadIdx.x;
  int w = tid>>6, lane = tid&63, l15 = lane&15, l4 = lane>>4;
  int blk = blockIdx.x, b = blk>>6, r0 = (blk&63)*32;

  // ---- phase A: gather P rows + gelu -> Af [row][k] fp32
  {
    int rr = tid&31, kb = (tid>>5)*32;
    int gr = b*LL + r0 + rr;
    int s = min(max(src[gr],0),49), rl = rel[gr]&1, t = min(max(tgt[gr],0),49);
    const float* ps = P + s*256;
    const float* pr = P + (50+rl)*256;
    const float* pt = P + (52+t)*256;
    #pragma unroll
    for(int j=0;j<32;j+=4){
      int k = kb+j;
      float4 vs = *(const float4*)(ps+k), vr = *(const float4*)(pr+k), vt = *(const float4*)(pt+k);
      float4 o;
      o.x = geluf(vs.x+vr.x+vt.x); o.y = geluf(vs.y+vr.y+vt.y);
      o.z = geluf(vs.z+vr.z+vt.z); o.w = geluf(vs.w+vr.w+vt.w);
      *(float4*)&Af[rr*AST + k] = o;
    }
  }
  __syncthreads();

  // ---- phase B: Xe = A @ ew2 + eb2, fp32-faithful via hi/lo split (3 MFMA terms)
  {
    f32x4 acc[2][4];
    #pragma unroll
    for(int mt=0;mt<2;mt++)
    #pragma unroll
    for(int nt=0;nt<4;nt++) acc[mt][nt] = (f32x4){0.f,0.f,0.f,0.f};
    for(int kc=0;kc<8;kc++){
      int k0 = kc*32 + l4*8;
      bf16x8 ah[2], al[2];
      #pragma unroll
      for(int mt=0;mt<2;mt++){
        const float* p = &Af[(mt*16+l15)*AST + k0];
        split8(*(const float4*)p, *(const float4*)(p+4), ah[mt], al[mt]);
      }
      #pragma unroll
      for(int nt=0;nt<4;nt++){
        int n = w*64 + nt*16 + l15;
        bf16x8 wh = *(const bf16x8*)&Weh[n*256 + k0];
        bf16x8 wl = *(const bf16x8*)&Wel[n*256 + k0];
        #pragma unroll
        for(int mt=0;mt<2;mt++){
          acc[mt][nt] = __builtin_amdgcn_mfma_f32_16x16x32_bf16(ah[mt], wh, acc[mt][nt], 0,0,0);
          acc[mt][nt] = __builtin_amdgcn_mfma_f32_16x16x32_bf16(ah[mt], wl, acc[mt][nt], 0,0,0);
          acc[mt][nt] = __builtin_amdgcn_mfma_f32_16x16x32_bf16(al[mt], wh, acc[mt][nt], 0,0,0);
        }
      }
    }
    #pragma unroll
    for(int nt=0;nt<4;nt++){
      int n = w*64 + nt*16 + l15;
      float bb = eb2[n];
      #pragma unroll
      for(int mt=0;mt<2;mt++)
      #pragma unroll
      for(int reg=0;reg<4;reg++){
        int r = mt*16 + l4*4 + reg;
        Xf[r*AST + n] = acc[mt][nt][reg] + bb;
      }
    }
  }
  __syncthreads();

  // ---- phase C: gate hidden (bf16 MFMA) + inline gate dot -> redG
  {
    f32x4 ag[2][4];
    #pragma unroll
    for(int mt=0;mt<2;mt++)
    #pragma unroll
    for(int nt=0;nt<4;nt++) ag[mt][nt] = (f32x4){0.f,0.f,0.f,0.f};
    for(int kc=0;kc<8;kc++){
      int k0 = kc*32 + l4*8;
      bf16x8 xa[2];
      #pragma unroll
      for(int mt=0;mt<2;mt++){
        const float* p = &Xf[(mt*16+l15)*AST + k0];
        xa[mt] = cvt8(*(const float4*)p, *(const float4*)(p+4));
      }
      #pragma unroll
      for(int nt=0;nt<4;nt++){
        int n = w*64 + nt*16 + l15;
        bf16x8 wv = *(const bf16x8*)&Wg[n*256 + k0];
        #pragma unroll
        for(int mt=0;mt<2;mt++)
          ag[mt][nt] = __builtin_amdgcn_mfma_f32_16x16x32_bf16(xa[mt], wv, ag[mt][nt], 0,0,0);
      }
    }
    float gpart[2][4] = {{0.f,0.f,0.f,0.f},{0.f,0.f,0.f,0.f}};
    #pragma unroll
    for(int nt=0;nt<4;nt++){
      int n = w*64 + nt*16 + l15;
      float gb = gb1[n], gw = gw2[n];
      #pragma unroll
      for(int mt=0;mt<2;mt++)
      #pragma unroll
      for(int reg=0;reg<4;reg++)
        gpart[mt][reg] += geluf(ag[mt][nt][reg] + gb)*gw;
    }
    #pragma unroll
    for(int mt=0;mt<2;mt++)
    #pragma unroll
    for(int reg=0;reg<4;reg++){
      float sv = gpart[mt][reg];
      #pragma unroll
      for(int o=1;o<16;o<<=1) sv += __shfl_xor(sv,o);
      if(l15==0) redG[(mt*16 + l4*4 + reg)*4 + w] = sv;
    }
  }
  // ---- phase D: routing projections (fp32, from fp32 Xe)
  {
    int r2 = tid>>3, g = tid&7, c0 = g*4;
    const float* W4 = (c0<16)? (gp + c0) : (sp + (c0-16));
    float4 p = {0.f,0.f,0.f,0.f};
    for(int k=0;k<256;k++){
      float x = Xf[r2*AST + k];
      float4 wv = *(const float4*)(W4 + k*16);
      p.x += x*wv.x; p.y += x*wv.y; p.z += x*wv.z; p.w += x*wv.w;
    }
    pv[r2*32+c0+0]=p.x; pv[r2*32+c0+1]=p.y; pv[r2*32+c0+2]=p.z; pv[r2*32+c0+3]=p.w;
  }
  __syncthreads();
  if(tid < 32){
    float ssum = redG[tid*4+0]+redG[tid*4+1]+redG[tid*4+2]+redG[tid*4+3] + gb2[0];
    gatev[tid] = 1.f/(1.f+expf(-ssum));
    float bg = pv[tid*32+0]; int big = 0;
    #pragma unroll
    for(int j=1;j<16;j++){ float x=pv[tid*32+j]; if(x>bg){bg=x;big=j;} }
    float bs = pv[tid*32+16]; int bis = 0;
    #pragma unroll
    for(int j=1;j<16;j++){ float x=pv[tid*32+16+j]; if(x>bs){bs=x;bis=j;} }
    nidx[tid] = big*16 + bis;
  }
  __syncthreads();

  // ---- phase E1: msg hidden (N=512) -> Mh bf16 (overlays Af)
  {
    f32x4 a1[2][8];
    #pragma unroll
    for(int mt=0;mt<2;mt++)
    #pragma unroll
    for(int nt=0;nt<8;nt++) a1[mt][nt] = (f32x4){0.f,0.f,0.f,0.f};
    for(int kc=0;kc<8;kc++){
      int k0 = kc*32 + l4*8;
      bf16x8 xa[2];
      #pragma unroll
      for(int mt=0;mt<2;mt++){
        const float* p = &Xf[(mt*16+l15)*AST + k0];
        xa[mt] = cvt8(*(const float4*)p, *(const float4*)(p+4));
      }
      #pragma unroll
      for(int nt=0;nt<8;nt++){
        int n = w*128 + nt*16 + l15;
        bf16x8 wv = *(const bf16x8*)&Wm1[n*256 + k0];
        #pragma unroll
        for(int mt=0;mt<2;mt++)
          a1[mt][nt] = __builtin_amdgcn_mfma_f32_16x16x32_bf16(xa[mt], wv, a1[mt][nt], 0,0,0);
      }
    }
    __syncthreads();   // all Af-region reads long done; now safe to overwrite with Mh
    #pragma unroll
    for(int nt=0;nt<8;nt++){
      int n = w*128 + nt*16 + l15;
      float mb = mb1[n];
      #pragma unroll
      for(int mt=0;mt<2;mt++)
      #pragma unroll
      for(int reg=0;reg<4;reg++){
        int r = mt*16 + l4*4 + reg;
        Mh[r*MST + n] = __float2bfloat16(geluf(a1[mt][nt][reg] + mb));
      }
    }
  }
  __syncthreads();

  // ---- phase E2: msg out (K=512) + phase F scatter
  {
    f32x4 a2[2][4];
    #pragma unroll
    for(int mt=0;mt<2;mt++)
    #pragma unroll
    for(int nt=0;nt<4;nt++) a2[mt][nt] = (f32x4){0.f,0.f,0.f,0.f};
    for(int kc=0;kc<16;kc++){
      int k0 = kc*32 + l4*8;
      bf16x8 ha[2];
      #pragma unroll
      for(int mt=0;mt<2;mt++) ha[mt] = *(const bf16x8*)&Mh[(mt*16+l15)*MST + k0];
      #pragma unroll
      for(int nt=0;nt<4;nt++){
        int n = w*64 + nt*16 + l15;
        bf16x8 wv = *(const bf16x8*)&Wm2[n*512 + k0];
        #pragma unroll
        for(int mt=0;mt<2;mt++)
          a2[mt][nt] = __builtin_amdgcn_mfma_f32_16x16x32_bf16(ha[mt], wv, a2[mt][nt], 0,0,0);
      }
    }
    #pragma unroll
    for(int nt=0;nt<4;nt++){
      int col = w*64 + nt*16 + l15;
      float mb = mb2[col];
      #pragma unroll
      for(int mt=0;mt<2;mt++)
      #pragma unroll
      for(int reg=0;reg<4;reg++){
        int r = mt*16 + l4*4 + reg;
        float val = (a2[mt][nt][reg] + mb)*gatev[r];
        atomicAdd(&incoming[((size_t)b*NNODE + nidx[r])*256 + col], val);
      }
    }
  }
}

// ---------------- K5: the 64 q-rows through msg/gate/route/scatter
__global__ __launch_bounds__(256) void k_qrow(const float* __restrict__ qv,
    const float* __restrict__ mw1, const float* __restrict__ mb1,
    const float* __restrict__ mw2, const float* __restrict__ mb2,
    const float* __restrict__ gw1, const float* __restrict__ gb1,
    const float* __restrict__ gw2, const float* __restrict__ gb2,
    const float* __restrict__ gp, const float* __restrict__ sp,
    float* __restrict__ incoming){
  __shared__ float x[256];
  __shared__ float mh[512];
  __shared__ float gh[256];
  __shared__ float pv[32];
  __shared__ float rbuf[4];
  __shared__ float gv;
  __shared__ int nn;
  int b = blockIdx.x, j = threadIdx.x;
  x[j] = qv[b*256+j];
  __syncthreads();
  float a0 = mb1[j], a1 = mb1[256+j], g0 = gb1[j];
  for(int k=0;k<256;k++){
    float xv = x[k];
    a0 += xv*mw1[k*512+j];
    a1 += xv*mw1[k*512+256+j];
    g0 += xv*gw1[k*256+j];
  }
  mh[j] = geluf(a0); mh[256+j] = geluf(a1); gh[j] = geluf(g0);
  if(j < 32){
    float s1 = 0.f;
    const float* wq = (j<16)? gp+j : sp+(j-16);
    for(int k=0;k<256;k++) s1 += x[k]*wq[k*16];
    pv[j] = s1;
  }
  __syncthreads();
  float m0 = mb2[j];
  for(int k=0;k<512;k++) m0 += mh[k]*mw2[k*256+j];
  float part = gh[j]*gw2[j];
  for(int o=32;o>0;o>>=1) part += __shfl_down(part,o);
  if((j&63)==0) rbuf[j>>6] = part;
  __syncthreads();
  if(j==0){
    float s1 = rbuf[0]+rbuf[1]+rbuf[2]+rbuf[3];
    gv = 1.f/(1.f+expf(-(s1 + gb2[0])));
    float bg = pv[0]; int big = 0;
    for(int t2=1;t2<16;t2++){ if(pv[t2]>bg){bg=pv[t2];big=t2;} }
    float bs = pv[16]; int bis = 0;
    for(int t2=1;t2<16;t2++){ if(pv[16+t2]>bs){bs=pv[16+t2];bis=t2;} }
    nn = big*16 + bis;
  }
  __syncthreads();
  atomicAdd(&incoming[((size_t)b*NNODE + nn)*256 + j], m0*gv);
}

// ---------------- K6: Cpre = incoming @ upd_w1[256:512] + upd_b1   (fp32, loop-invariant)
__device__ __forceinline__ void fma32_2q(const float* Arow, float w0, float w1, float* acc0, float* acc1){
  const float4* ap = (const float4*)Arow;
  #pragma unroll
  for(int i=0;i<8;i++){
    float4 a = ap[i];
    acc0[i*4+0] += a.x*w0; acc0[i*4+1] += a.y*w0;
    acc0[i*4+2] += a.z*w0; acc0[i*4+3] += a.w*w0;
    acc1[i*4+0] += a.x*w1; acc1[i*4+1] += a.y*w1;
    acc1[i*4+2] += a.z*w1; acc1[i*4+3] += a.w*w1;
  }
}
__global__ __launch_bounds__(256,2) void k_cpre(const float* __restrict__ incoming,
    const float* __restrict__ uw1, const float* __restrict__ ub1, float* __restrict__ Cpre){
  __shared__ float ATl[256*32];
  int blk = blockIdx.x, row0 = blk*32;
  int tid = threadIdx.x, rr = tid&31, kb = (tid>>5)*32;
  const float* ip = incoming + (size_t)(row0+rr)*256;
  #pragma unroll
  for(int j=0;j<32;j+=4){
    float4 v = *(const float4*)(ip+kb+j);
    ATl[(kb+j+0)*32+rr]=v.x; ATl[(kb+j+1)*32+rr]=v.y;
    ATl[(kb+j+2)*32+rr]=v.z; ATl[(kb+j+3)*32+rr]=v.w;
  }
  __syncthreads();
  float acc0[32], acc1[32];
  #pragma unroll
  for(int r=0;r<32;r++){acc0[r]=0.f;acc1[r]=0.f;}
  int c = tid;
  float w0 = uw1[256*512 + c], w1 = uw1[256*512 + 256 + c];
  for(int k=0;k<256;k++){
    float w0n = (k<255)? uw1[(257+k)*512 + c] : 0.f;
    float w1n = (k<255)? uw1[(257+k)*512 + 256 + c] : 0.f;
    fma32_2q(&ATl[k*32], w0, w1, acc0, acc1);
    w0 = w0n; w1 = w1n;
  }
  float b0 = ub1[c], b1 = ub1[256+c];
  #pragma unroll
  for(int r=0;r<32;r++){
    size_t ro = (size_t)(row0+r)*512;
    Cpre[ro+c]     = acc0[r]+b0;
    Cpre[ro+256+c] = acc1[r]+b1;
  }
}

// ---------------- persistent 32-step update: MFMA bf16, fp32 state/LN
#define SROW 264
#define HROW 520
__global__ __launch_bounds__(256,2) void k_steps(
    const float* __restrict__ Sini, const float* __restrict__ Cpre,
    const bf16* __restrict__ WTa, const bf16* __restrict__ WT2,
    const float* __restrict__ ub2, const float* __restrict__ lnw,
    const float* __restrict__ lnb, float* __restrict__ Sout)
{
  __shared__ __align__(16) bf16 Sbf[32*SROW];
  __shared__ __align__(16) bf16 Hbf[32*HROW];
  __shared__ float redA[32*4], redB[32*4];

  int tid = threadIdx.x;
  int w   = tid >> 6;
  int lane= tid & 63;
  int l15 = lane & 15;
  int l4  = lane >> 4;
  int row0 = blockIdx.x * 32;

  f32x4 Sreg[2][4];
  float ub[4], lw[4], lb[4];
  #pragma unroll
  for(int nt=0;nt<4;nt++){
    int col = w*64 + nt*16 + l15;
    ub[nt] = ub2[col]; lw[nt] = lnw[col]; lb[nt] = lnb[col];
  }
  #pragma unroll
  for(int mt=0;mt<2;mt++)
  #pragma unroll
  for(int nt=0;nt<4;nt++){
    int col = w*64 + nt*16 + l15;
    #pragma unroll
    for(int reg=0;reg<4;reg++){
      int r = mt*16 + l4*4 + reg;
      int node = (row0 + r) & 255;
      float v = Sini[node*256 + col];
      Sreg[mt][nt][reg] = v;
      Sbf[r*SROW + col] = __float2bfloat16(v);
    }
  }
  __syncthreads();

  const float* CpreBlk = Cpre + (size_t)row0*512;

  for(int step=0; step<NSTEPS; step++){
    f32x4 acc1[2][8];
    #pragma unroll
    for(int mt=0;mt<2;mt++)
    #pragma unroll
    for(int nt=0;nt<8;nt++) acc1[mt][nt] = (f32x4){0.f,0.f,0.f,0.f};
    for(int kc=0;kc<8;kc++){
      int k0 = kc*32 + l4*8;
      bf16x8 a0 = *(const bf16x8*)&Sbf[(     l15)*SROW + k0];
      bf16x8 a1 = *(const bf16x8*)&Sbf[(16 + l15)*SROW + k0];
      #pragma unroll
      for(int nt=0;nt<8;nt++){
        int n = w*128 + nt*16 + l15;
        bf16x8 bfr = *(const bf16x8*)&WTa[n*256 + k0];
        acc1[0][nt] = __builtin_amdgcn_mfma_f32_16x16x32_bf16(a0, bfr, acc1[0][nt], 0,0,0);
        acc1[1][nt] = __builtin_amdgcn_mfma_f32_16x16x32_bf16(a1, bfr, acc1[1][nt], 0,0,0);
      }
    }
    #pragma unroll
    for(int mt=0;mt<2;mt++)
    #pragma unroll
    for(int nt=0;nt<8;nt++){
      int n = w*128 + nt*16 + l15;
      #pragma unroll
      for(int reg=0;reg<4;reg++){
        int r = mt*16 + l4*4 + reg;
        float h = geluf(acc1[mt][nt][reg] + CpreBlk[(size_t)r*512 + n]);
        Hbf[r*HROW + n] = __float2bfloat16(h);
      }
    }
    __syncthreads();

    f32x4 acc2[2][4];
    #pragma unroll
    for(int mt=0;mt<2;mt++)
    #pragma unroll
    for(int nt=0;nt<4;nt++) acc2[mt][nt] = (f32x4){0.f,0.f,0.f,0.f};
    for(int kc=0;kc<16;kc++){
      int k0 = kc*32 + l4*8;
      bf16x8 a0 = *(const bf16x8*)&Hbf[(     l15)*HROW + k0];
      bf16x8 a1 = *(const bf16x8*)&Hbf[(16 + l15)*HROW + k0];
      #pragma unroll
      for(int nt=0;nt<4;nt++){
        int n = w*64 + nt*16 + l15;
        bf16x8 bfr = *(const bf16x8*)&WT2[n*512 + k0];
        acc2[0][nt] = __builtin_amdgcn_mfma_f32_16x16x32_bf16(a0, bfr, acc2[0][nt], 0,0,0);
        acc2[1][nt] = __builtin_amdgcn_mfma_f32_16x16x32_bf16(a1, bfr, acc2[1][nt], 0,0,0);
      }
    }
    #pragma unroll
    for(int mt=0;mt<2;mt++)
    #pragma unroll
    for(int nt=0;nt<4;nt++)
    #pragma unroll
    for(int reg=0;reg<4;reg++)
      acc2[mt][nt][reg] = Sreg[mt][nt][reg] + acc2[mt][nt][reg] + ub[nt];

    #pragma unroll
    for(int mt=0;mt<2;mt++)
    #pragma unroll
    for(int reg=0;reg<4;reg++){
      float s1 = 0.f, s2 = 0.f;
      #pragma unroll
      for(int nt=0;nt<4;nt++){ float v = acc2[mt][nt][reg]; s1 += v; s2 += v*v; }
      #pragma unroll
      for(int o=1;o<16;o<<=1){ s1 += __shfl_xor(s1,o); s2 += __shfl_xor(s2,o); }
      if(l15 == 0){
        int r = mt*16 + l4*4 + reg;
        redA[r*4+w] = s1; redB[r*4+w] = s2;
      }
    }
    __syncthreads();

    #pragma unroll
    for(int mt=0;mt<2;mt++)
    #pragma unroll
    for(int reg=0;reg<4;reg++){
      int r = mt*16 + l4*4 + reg;
      float ss = redA[r*4+0]+redA[r*4+1]+redA[r*4+2]+redA[r*4+3];
      float qq = redB[r*4+0]+redB[r*4+1]+redB[r*4+2]+redB[r*4+3];
      float mu = ss*(1.f/256.f);
      float rs = rsqrtf(qq*(1.f/256.f) - mu*mu + 1e-5f);
      #pragma unroll
      for(int nt=0;nt<4;nt++){
        int col = w*64 + nt*16 + l15;
        float sv = (acc2[mt][nt][reg]-mu)*rs*lw[nt] + lb[nt];
        Sreg[mt][nt][reg] = sv;
        Sbf[r*SROW + col] = __float2bfloat16(sv);
      }
    }
    __syncthreads();
  }

  #pragma unroll
  for(int mt=0;mt<2;mt++)
  #pragma unroll
  for(int nt=0;nt<4;nt++){
    int col = w*64 + nt*16 + l15;
    #pragma unroll
    for(int reg=0;reg<4;reg++){
      int r = mt*16 + l4*4 + reg;
      Sout[(size_t)(row0+r)*256 + col] = Sreg[mt][nt][reg];
    }
  }
}

// ---------------- head
__global__ __launch_bounds__(256) void k_head(const int* __restrict__ qsrc, const int* __restrict__ qtgt,
    const float* __restrict__ S, const float* __restrict__ hw1, const float* __restrict__ hb1,
    const float* __restrict__ hw2, const float* __restrict__ hb2, float* __restrict__ out){
  __shared__ float a[512];
  __shared__ float h[256];
  __shared__ float rbuf[8];
  int b = blockIdx.x, j = threadIdx.x;
  int s = min(max(qsrc[b],0),255), t = min(max(qtgt[b],0),255);
  a[j]     = S[((size_t)b*NNODE + s)*256 + j];
  a[256+j] = S[((size_t)b*NNODE + t)*256 + j];
  __syncthreads();
  float acc = hb1[j];
  for(int k=0;k<512;k++) acc += a[k]*hw1[k*256+j];
  h[j] = geluf(acc);
  __syncthreads();
  float p0 = h[j]*hw2[j*2], p1 = h[j]*hw2[j*2+1];
  for(int o=32;o>0;o>>=1){ p0 += __shfl_down(p0,o); p1 += __shfl_down(p1,o); }
  if((j&63)==0){ rbuf[(j>>6)*2] = p0; rbuf[(j>>6)*2+1] = p1; }
  __syncthreads();
  if(j==0){
    out[b*2+0] = rbuf[0]+rbuf[2]+rbuf[4]+rbuf[6] + hb2[0];
    out[b*2+1] = rbuf[1]+rbuf[3]+rbuf[5]+rbuf[7] + hb2[1];
  }
}

extern "C" void kernel_launch(void* const* d_in, const int* in_sizes, int n_in,
                              void* d_out, int out_size, void* d_ws, size_t ws_size,
                              hipStream_t stream){
  (void)in_sizes; (void)n_in; (void)out_size; (void)ws_size;
  const int*  src  = (const int*)d_in[0];
  const int*  rel  = (const int*)d_in[1];
  const int*  tgt  = (const int*)d_in[2];
  const int*  qsrc = (const int*)d_in[4];
  const int*  qtgt = (const int*)d_in[5];
  const float* ne  = (const float*)d_in[6];
  const float* re  = (const float*)d_in[7];
  const float* ew1 = (const float*)d_in[8];  const float* eb1 = (const float*)d_in[9];
  const float* ew2 = (const float*)d_in[10]; const float* eb2 = (const float*)d_in[11];
  const float* qw1 = (const float*)d_in[12]; const float* qb1 = (const float*)d_in[13];
  const float* qw2 = (const float*)d_in[14]; const float* qb2 = (const float*)d_in[15];
  const float* gp  = (const float*)d_in[16]; const float* sp  = (const float*)d_in[17];
  const float* mw1 = (const float*)d_in[18]; const float* mb1 = (const float*)d_in[19];
  const float* mw2 = (const float*)d_in[20]; const float* mb2 = (const float*)d_in[21];
  const float* gw1 = (const float*)d_in[22]; const float* gb1 = (const float*)d_in[23];
  const float* gw2 = (const float*)d_in[24]; const float* gb2 = (const float*)d_in[25];
  const float* uw1 = (const float*)d_in[26]; const float* ub1 = (const float*)d_in[27];
  const float* uw2 = (const float*)d_in[28]; const float* ub2 = (const float*)d_in[29];
  const float* lnw = (const float*)d_in[30]; const float* lnb = (const float*)d_in[31];
  const float* Sini= (const float*)d_in[32];
  const float* hw1 = (const float*)d_in[33]; const float* hb1 = (const float*)d_in[34];
  const float* hw2 = (const float*)d_in[35]; const float* hb2 = (const float*)d_in[36];

  float* ws = (float*)d_ws;
  float* P        = ws;                  //    26112
  float* qv       = ws + 26112;          //    16384
  float* incoming = ws + 42496;          //  4194304
  float* Cpre     = ws + 4236800;        //  8388608
  float* Sout     = ws + 12625408;       //  4194304
  bf16*  wb       = (bf16*)(ws + 16819712);
  bf16*  WTa = wb;            bf16* WT2 = wb + 131072;
  bf16*  Weh = wb + 262144;   bf16* Wel = wb + 327680;
  bf16*  Wg  = wb + 393216;
  bf16*  Wm1 = wb + 458752;   bf16* Wm2 = wb + 589824;
  float* out = (float*)d_out;

  hipMemsetAsync(incoming, 0, (size_t)4194304*4, stream);
  k_wprep<<<512,256,0,stream>>>(uw1,uw2,ew2,gw1,mw1,mw2,WTa,WT2,Weh,Wel,Wg,Wm1,Wm2);
  k_precompute<<<102,256,0,stream>>>(ne,re,ew1,eb1,P);
  k_query<<<64,256,0,stream>>>(qsrc,qtgt,ne,qw1,qb1,qw2,qb2,qv);
  k_edge_mfma<<<4096,256,0,stream>>>(src,rel,tgt,P,Weh,Wel,eb2,Wg,gb1,gw2,gb2,gp,sp,Wm1,mb1,Wm2,mb2,incoming);
  k_qrow<<<64,256,0,stream>>>(qv,mw1,mb1,mw2,mb2,gw1,gb1,gw2,gb2,gp,sp,incoming);
  k_cpre<<<512,256,0,stream>>>(incoming,uw1,ub1,Cpre);
  k_steps<<<512,256,0,stream>>>(Sini,Cpre,WTa,WT2,ub2,lnw,lnb,Sout);
  k_head<<<64,256,0,stream>>>(qsrc,qtgt,Sout,hw1,hb1,hw2,hb2,out);
}

// Round 5
// 3326.588 us; speedup vs baseline: 2.6268x; 1.0539x over previous
//
#include <hip/hip_runtime.h>
#include <hip/hip_bf16.h>
#include <math.h>

#define NB     64
#define LL     2048
#define DD     256
#define NNODE  256     // G*K
#define NSTEPS 32

typedef __hip_bfloat16 bf16;
typedef __attribute__((ext_vector_type(8))) short bf16x8;
typedef __attribute__((ext_vector_type(4))) float f32x4;

__device__ __forceinline__ float geluf(float x){ return 0.5f*x*(1.0f+erff(x*0.70710678118654752440f)); }
__device__ __forceinline__ short f2bs(float x){ bf16 h = __float2bfloat16(x); return __builtin_bit_cast(short, h); }
__device__ __forceinline__ float bs2f(short s){ bf16 h = __builtin_bit_cast(bf16, s); return __bfloat162float(h); }

// build bf16 hi/lo split fragment from 8 fp32 values
__device__ __forceinline__ void split8(float4 a, float4 b, bf16x8& hi, bf16x8& lo){
  float av[8] = {a.x,a.y,a.z,a.w,b.x,b.y,b.z,b.w};
  #pragma unroll
  for(int j=0;j<8;j++){
    short h = f2bs(av[j]);
    hi[j] = h;
    lo[j] = f2bs(av[j] - bs2f(h));
  }
}
__device__ __forceinline__ bf16x8 cvt8(float4 a, float4 b){
  float av[8] = {a.x,a.y,a.z,a.w,b.x,b.y,b.z,b.w};
  bf16x8 v;
  #pragma unroll
  for(int j=0;j<8;j++) v[j] = f2bs(av[j]);
  return v;
}

// ---------------- K1: P tables: rows 0..49 src-part, 50..51 rel-part(+eb1), 52..101 tgt-part
__global__ __launch_bounds__(256) void k_precompute(const float* __restrict__ ne,
    const float* __restrict__ re, const float* __restrict__ ew1, const float* __restrict__ eb1,
    float* __restrict__ P){
  __shared__ float a[256];
  int row = blockIdx.x, j = threadIdx.x;
  const float* vec; const float* W;
  if(row < 50){ vec = ne + row*256; W = ew1; }
  else if(row < 52){ vec = re + (row-50)*256; W = ew1 + 256*256; }
  else { vec = ne + (row-52)*256; W = ew1 + 512*256; }
  a[j] = vec[j];
  __syncthreads();
  float acc = 0.f;
  for(int k=0;k<256;k++) acc += a[k]*W[k*256 + j];
  if(row >= 50 && row < 52) acc += eb1[j];
  P[row*256 + j] = acc;
}

// ---------------- K2: q[b] = MLP2(concat(ne[qsrc], ne[qtgt]))
__global__ __launch_bounds__(256) void k_query(const int* __restrict__ qsrc, const int* __restrict__ qtgt,
    const float* __restrict__ ne, const float* __restrict__ qw1, const float* __restrict__ qb1,
    const float* __restrict__ qw2, const float* __restrict__ qb2, float* __restrict__ qv){
  __shared__ float a[512];
  __shared__ float h[256];
  int b = blockIdx.x, j = threadIdx.x;
  int s = min(max(qsrc[b],0),49), t = min(max(qtgt[b],0),49);
  a[j]     = ne[s*256 + j];
  a[256+j] = ne[t*256 + j];
  __syncthreads();
  float acc = qb1[j];
  for(int k=0;k<512;k++) acc += a[k]*qw1[k*256+j];
  h[j] = geluf(acc);
  __syncthreads();
  float acc2 = qb2[j];
  for(int k=0;k<256;k++) acc2 += h[k]*qw2[k*256+j];
  qv[b*256+j] = acc2;
}

// ---------------- weight prep: all transposed [n][k] bf16 (hi, and hi/lo for ew2)
__global__ __launch_bounds__(256) void k_wprep(
    const float* __restrict__ uw1, const float* __restrict__ uw2,
    const float* __restrict__ ew2, const float* __restrict__ gw1,
    const float* __restrict__ mw1, const float* __restrict__ mw2,
    bf16* __restrict__ WTa, bf16* __restrict__ WT2,
    bf16* __restrict__ Weh, bf16* __restrict__ Wel, bf16* __restrict__ Wg,
    bf16* __restrict__ Wm1, bf16* __restrict__ Wm2){
  int i = blockIdx.x*256 + threadIdx.x;   // 0 .. 131071
  { int n = i >> 8, k = i & 255;  WTa[i] = __float2bfloat16(uw1[k*512 + n]); }
  { int n = i >> 9, k = i & 511;  WT2[i] = __float2bfloat16(uw2[k*256 + n]); }
  { int n = i >> 8, k = i & 255;  Wm1[i] = __float2bfloat16(mw1[k*512 + n]); }
  { int n = i >> 9, k = i & 511;  Wm2[i] = __float2bfloat16(mw2[k*256 + n]); }
  if(i < 65536){
    int n = i >> 8, k = i & 255;
    float v = ew2[k*256 + n];
    bf16 h = __float2bfloat16(v);
    Weh[i] = h;
    Wel[i] = __float2bfloat16(v - __bfloat162float(h));
    Wg[i]  = __float2bfloat16(gw1[k*256 + n]);
  }
}

// ---------------- K4: MFMA edge pipeline: gather->edge GEMM(split)->gate/route->msg->scatter
#define AST 260   // fp32 LDS row stride (1040B: 16B-aligned, bank-balanced)
#define MST 520   // bf16 LDS row stride (1040B)
__global__ __launch_bounds__(256,2) void k_edge_mfma(
    const int* __restrict__ src, const int* __restrict__ rel, const int* __restrict__ tgt,
    const float* __restrict__ P,
    const bf16* __restrict__ Weh, const bf16* __restrict__ Wel, const float* __restrict__ eb2,
    const bf16* __restrict__ Wg, const float* __restrict__ gb1,
    const float* __restrict__ gw2, const float* __restrict__ gb2,
    const float* __restrict__ gp, const float* __restrict__ sp,
    const bf16* __restrict__ Wm1, const float* __restrict__ mb1,
    const bf16* __restrict__ Wm2, const float* __restrict__ mb2,
    float* __restrict__ incoming)
{
  __shared__ __align__(16) float Af[32*AST];   // fp32 gelu'd edge-hidden; overlaid by Mh (bf16) from E1 on
  __shared__ __align__(16) float Xf[32*AST];   // fp32 Xe
  __shared__ float pv[32*32];
  __shared__ float redG[32*4];
  __shared__ float gatev[32];
  __shared__ int   nidx[32];
  bf16* Mh = (bf16*)Af;    // 32*520*2 B == 32*260*4 B exactly

  int tid = threadIdx.x;
  int w = tid>>6, lane = tid&63, l15 = lane&15, l4 = lane>>4;
  int blk = blockIdx.x, b = blk>>6, r0 = (blk&63)*32;

  // ---- phase A: gather P rows + gelu -> Af [row][k] fp32
  {
    int rr = tid&31, kb = (tid>>5)*32;
    int gr = b*LL + r0 + rr;
    int s = min(max(src[gr],0),49), rl = rel[gr]&1, t = min(max(tgt[gr],0),49);
    const float* ps = P + s*256;
    const float* pr = P + (50+rl)*256;
    const float* pt = P + (52+t)*256;
    #pragma unroll
    for(int j=0;j<32;j+=4){
      int k = kb+j;
      float4 vs = *(const float4*)(ps+k), vr = *(const float4*)(pr+k), vt = *(const float4*)(pt+k);
      float4 o;
      o.x = geluf(vs.x+vr.x+vt.x); o.y = geluf(vs.y+vr.y+vt.y);
      o.z = geluf(vs.z+vr.z+vt.z); o.w = geluf(vs.w+vr.w+vt.w);
      *(float4*)&Af[rr*AST + k] = o;
    }
  }
  __syncthreads();

  // ---- phase B: Xe = A @ ew2 + eb2, fp32-faithful via hi/lo split (3 MFMA terms)
  {
    f32x4 acc[2][4];
    #pragma unroll
    for(int mt=0;mt<2;mt++)
    #pragma unroll
    for(int nt=0;nt<4;nt++) acc[mt][nt] = (f32x4){0.f,0.f,0.f,0.f};
    for(int kc=0;kc<8;kc++){
      int k0 = kc*32 + l4*8;
      bf16x8 ah[2], al[2];
      #pragma unroll
      for(int mt=0;mt<2;mt++){
        const float* p = &Af[(mt*16+l15)*AST + k0];
        split8(*(const float4*)p, *(const float4*)(p+4), ah[mt], al[mt]);
      }
      #pragma unroll
      for(int nt=0;nt<4;nt++){
        int n = w*64 + nt*16 + l15;
        bf16x8 wh = *(const bf16x8*)&Weh[n*256 + k0];
        bf16x8 wl = *(const bf16x8*)&Wel[n*256 + k0];
        #pragma unroll
        for(int mt=0;mt<2;mt++){
          acc[mt][nt] = __builtin_amdgcn_mfma_f32_16x16x32_bf16(ah[mt], wh, acc[mt][nt], 0,0,0);
          acc[mt][nt] = __builtin_amdgcn_mfma_f32_16x16x32_bf16(ah[mt], wl, acc[mt][nt], 0,0,0);
          acc[mt][nt] = __builtin_amdgcn_mfma_f32_16x16x32_bf16(al[mt], wh, acc[mt][nt], 0,0,0);
        }
      }
    }
    #pragma unroll
    for(int nt=0;nt<4;nt++){
      int n = w*64 + nt*16 + l15;
      float bb = eb2[n];
      #pragma unroll
      for(int mt=0;mt<2;mt++)
      #pragma unroll
      for(int reg=0;reg<4;reg++){
        int r = mt*16 + l4*4 + reg;
        Xf[r*AST + n] = acc[mt][nt][reg] + bb;
      }
    }
  }
  __syncthreads();

  // ---- phase C: gate hidden (bf16 MFMA) + inline gate dot -> redG
  {
    f32x4 ag[2][4];
    #pragma unroll
    for(int mt=0;mt<2;mt++)
    #pragma unroll
    for(int nt=0;nt<4;nt++) ag[mt][nt] = (f32x4){0.f,0.f,0.f,0.f};
    for(int kc=0;kc<8;kc++){
      int k0 = kc*32 + l4*8;
      bf16x8 xa[2];
      #pragma unroll
      for(int mt=0;mt<2;mt++){
        const float* p = &Xf[(mt*16+l15)*AST + k0];
        xa[mt] = cvt8(*(const float4*)p, *(const float4*)(p+4));
      }
      #pragma unroll
      for(int nt=0;nt<4;nt++){
        int n = w*64 + nt*16 + l15;
        bf16x8 wv = *(const bf16x8*)&Wg[n*256 + k0];
        #pragma unroll
        for(int mt=0;mt<2;mt++)
          ag[mt][nt] = __builtin_amdgcn_mfma_f32_16x16x32_bf16(xa[mt], wv, ag[mt][nt], 0,0,0);
      }
    }
    float gpart[2][4] = {{0.f,0.f,0.f,0.f},{0.f,0.f,0.f,0.f}};
    #pragma unroll
    for(int nt=0;nt<4;nt++){
      int n = w*64 + nt*16 + l15;
      float gb = gb1[n], gw = gw2[n];
      #pragma unroll
      for(int mt=0;mt<2;mt++)
      #pragma unroll
      for(int reg=0;reg<4;reg++)
        gpart[mt][reg] += geluf(ag[mt][nt][reg] + gb)*gw;
    }
    #pragma unroll
    for(int mt=0;mt<2;mt++)
    #pragma unroll
    for(int reg=0;reg<4;reg++){
      float sv = gpart[mt][reg];
      #pragma unroll
      for(int o=1;o<16;o<<=1) sv += __shfl_xor(sv,o);
      if(l15==0) redG[(mt*16 + l4*4 + reg)*4 + w] = sv;
    }
  }
  // ---- phase D: routing projections (fp32, from fp32 Xe)
  {
    int r2 = tid>>3, g = tid&7, c0 = g*4;
    const float* W4 = (c0<16)? (gp + c0) : (sp + (c0-16));
    float4 p = {0.f,0.f,0.f,0.f};
    for(int k=0;k<256;k++){
      float x = Xf[r2*AST + k];
      float4 wv = *(const float4*)(W4 + k*16);
      p.x += x*wv.x; p.y += x*wv.y; p.z += x*wv.z; p.w += x*wv.w;
    }
    pv[r2*32+c0+0]=p.x; pv[r2*32+c0+1]=p.y; pv[r2*32+c0+2]=p.z; pv[r2*32+c0+3]=p.w;
  }
  __syncthreads();
  if(tid < 32){
    float ssum = redG[tid*4+0]+redG[tid*4+1]+redG[tid*4+2]+redG[tid*4+3] + gb2[0];
    gatev[tid] = 1.f/(1.f+expf(-ssum));
    float bg = pv[tid*32+0]; int big = 0;
    #pragma unroll
    for(int j=1;j<16;j++){ float x=pv[tid*32+j]; if(x>bg){bg=x;big=j;} }
    float bs = pv[tid*32+16]; int bis = 0;
    #pragma unroll
    for(int j=1;j<16;j++){ float x=pv[tid*32+16+j]; if(x>bs){bs=x;bis=j;} }
    nidx[tid] = big*16 + bis;
  }
  __syncthreads();

  // ---- phase E1: msg hidden (N=512) -> Mh bf16 (overlays Af)
  {
    f32x4 a1[2][8];
    #pragma unroll
    for(int mt=0;mt<2;mt++)
    #pragma unroll
    for(int nt=0;nt<8;nt++) a1[mt][nt] = (f32x4){0.f,0.f,0.f,0.f};
    for(int kc=0;kc<8;kc++){
      int k0 = kc*32 + l4*8;
      bf16x8 xa[2];
      #pragma unroll
      for(int mt=0;mt<2;mt++){
        const float* p = &Xf[(mt*16+l15)*AST + k0];
        xa[mt] = cvt8(*(const float4*)p, *(const float4*)(p+4));
      }
      #pragma unroll
      for(int nt=0;nt<8;nt++){
        int n = w*128 + nt*16 + l15;
        bf16x8 wv = *(const bf16x8*)&Wm1[n*256 + k0];
        #pragma unroll
        for(int mt=0;mt<2;mt++)
          a1[mt][nt] = __builtin_amdgcn_mfma_f32_16x16x32_bf16(xa[mt], wv, a1[mt][nt], 0,0,0);
      }
    }
    __syncthreads();   // all Af-region reads long done; now safe to overwrite with Mh
    #pragma unroll
    for(int nt=0;nt<8;nt++){
      int n = w*128 + nt*16 + l15;
      float mb = mb1[n];
      #pragma unroll
      for(int mt=0;mt<2;mt++)
      #pragma unroll
      for(int reg=0;reg<4;reg++){
        int r = mt*16 + l4*4 + reg;
        Mh[r*MST + n] = __float2bfloat16(geluf(a1[mt][nt][reg] + mb));
      }
    }
  }
  __syncthreads();

  // ---- phase E2: msg out (K=512) + phase F scatter
  {
    f32x4 a2[2][4];
    #pragma unroll
    for(int mt=0;mt<2;mt++)
    #pragma unroll
    for(int nt=0;nt<4;nt++) a2[mt][nt] = (f32x4){0.f,0.f,0.f,0.f};
    for(int kc=0;kc<16;kc++){
      int k0 = kc*32 + l4*8;
      bf16x8 ha[2];
      #pragma unroll
      for(int mt=0;mt<2;mt++) ha[mt] = *(const bf16x8*)&Mh[(mt*16+l15)*MST + k0];
      #pragma unroll
      for(int nt=0;nt<4;nt++){
        int n = w*64 + nt*16 + l15;
        bf16x8 wv = *(const bf16x8*)&Wm2[n*512 + k0];
        #pragma unroll
        for(int mt=0;mt<2;mt++)
          a2[mt][nt] = __builtin_amdgcn_mfma_f32_16x16x32_bf16(ha[mt], wv, a2[mt][nt], 0,0,0);
      }
    }
    #pragma unroll
    for(int nt=0;nt<4;nt++){
      int col = w*64 + nt*16 + l15;
      float mb = mb2[col];
      #pragma unroll
      for(int mt=0;mt<2;mt++)
      #pragma unroll
      for(int reg=0;reg<4;reg++){
        int r = mt*16 + l4*4 + reg;
        float val = (a2[mt][nt][reg] + mb)*gatev[r];
        atomicAdd(&incoming[((size_t)b*NNODE + nidx[r])*256 + col], val);
      }
    }
  }
}

// ---------------- K5: the 64 q-rows through msg/gate/route/scatter
__global__ __launch_bounds__(256) void k_qrow(const float* __restrict__ qv,
    const float* __restrict__ mw1, const float* __restrict__ mb1,
    const float* __restrict__ mw2, const float* __restrict__ mb2,
    const float* __restrict__ gw1, const float* __restrict__ gb1,
    const float* __restrict__ gw2, const float* __restrict__ gb2,
    const float* __restrict__ gp, const float* __restrict__ sp,
    float* __restrict__ incoming){
  __shared__ float x[256];
  __shared__ float mh[512];
  __shared__ float gh[256];
  __shared__ float pv[32];
  __shared__ float rbuf[4];
  __shared__ float gv;
  __shared__ int nn;
  int b = blockIdx.x, j = threadIdx.x;
  x[j] = qv[b*256+j];
  __syncthreads();
  float a0 = mb1[j], a1 = mb1[256+j], g0 = gb1[j];
  for(int k=0;k<256;k++){
    float xv = x[k];
    a0 += xv*mw1[k*512+j];
    a1 += xv*mw1[k*512+256+j];
    g0 += xv*gw1[k*256+j];
  }
  mh[j] = geluf(a0); mh[256+j] = geluf(a1); gh[j] = geluf(g0);
  if(j < 32){
    float s1 = 0.f;
    const float* wq = (j<16)? gp+j : sp+(j-16);
    for(int k=0;k<256;k++) s1 += x[k]*wq[k*16];
    pv[j] = s1;
  }
  __syncthreads();
  float m0 = mb2[j];
  for(int k=0;k<512;k++) m0 += mh[k]*mw2[k*256+j];
  float part = gh[j]*gw2[j];
  for(int o=32;o>0;o>>=1) part += __shfl_down(part,o);
  if((j&63)==0) rbuf[j>>6] = part;
  __syncthreads();
  if(j==0){
    float s1 = rbuf[0]+rbuf[1]+rbuf[2]+rbuf[3];
    gv = 1.f/(1.f+expf(-(s1 + gb2[0])));
    float bg = pv[0]; int big = 0;
    for(int t2=1;t2<16;t2++){ if(pv[t2]>bg){bg=pv[t2];big=t2;} }
    float bs = pv[16]; int bis = 0;
    for(int t2=1;t2<16;t2++){ if(pv[16+t2]>bs){bs=pv[16+t2];bis=t2;} }
    nn = big*16 + bis;
  }
  __syncthreads();
  atomicAdd(&incoming[((size_t)b*NNODE + nn)*256 + j], m0*gv);
}

// ---------------- K6: Cpre = incoming @ upd_w1[256:512] + upd_b1   (fp32, loop-invariant)
__device__ __forceinline__ void fma32_2q(const float* Arow, float w0, float w1, float* acc0, float* acc1){
  const float4* ap = (const float4*)Arow;
  #pragma unroll
  for(int i=0;i<8;i++){
    float4 a = ap[i];
    acc0[i*4+0] += a.x*w0; acc0[i*4+1] += a.y*w0;
    acc0[i*4+2] += a.z*w0; acc0[i*4+3] += a.w*w0;
    acc1[i*4+0] += a.x*w1; acc1[i*4+1] += a.y*w1;
    acc1[i*4+2] += a.z*w1; acc1[i*4+3] += a.w*w1;
  }
}
__global__ __launch_bounds__(256,2) void k_cpre(const float* __restrict__ incoming,
    const float* __restrict__ uw1, const float* __restrict__ ub1, float* __restrict__ Cpre){
  __shared__ float ATl[256*32];
  int blk = blockIdx.x, row0 = blk*32;
  int tid = threadIdx.x, rr = tid&31, kb = (tid>>5)*32;
  const float* ip = incoming + (size_t)(row0+rr)*256;
  #pragma unroll
  for(int j=0;j<32;j+=4){
    float4 v = *(const float4*)(ip+kb+j);
    ATl[(kb+j+0)*32+rr]=v.x; ATl[(kb+j+1)*32+rr]=v.y;
    ATl[(kb+j+2)*32+rr]=v.z; ATl[(kb+j+3)*32+rr]=v.w;
  }
  __syncthreads();
  float acc0[32], acc1[32];
  #pragma unroll
  for(int r=0;r<32;r++){acc0[r]=0.f;acc1[r]=0.f;}
  int c = tid;
  float w0 = uw1[256*512 + c], w1 = uw1[256*512 + 256 + c];
  for(int k=0;k<256;k++){
    float w0n = (k<255)? uw1[(257+k)*512 + c] : 0.f;
    float w1n = (k<255)? uw1[(257+k)*512 + 256 + c] : 0.f;
    fma32_2q(&ATl[k*32], w0, w1, acc0, acc1);
    w0 = w0n; w1 = w1n;
  }
  float b0 = ub1[c], b1 = ub1[256+c];
  #pragma unroll
  for(int r=0;r<32;r++){
    size_t ro = (size_t)(row0+r)*512;
    Cpre[ro+c]     = acc0[r]+b0;
    Cpre[ro+256+c] = acc1[r]+b1;
  }
}

// ---------------- persistent 32-step update: MFMA bf16, fp32 state/LN
// M=64 rows/block, 512 threads (8 waves), grid 256, 1 block/CU.
// Weights stay L2-resident (Cpre bypasses L2 via nontemporal loads).
#define SROW 264
#define HROW 520
__global__ __launch_bounds__(512,2) void k_steps(
    const float* __restrict__ Sini, const float* __restrict__ Cpre,
    const bf16* __restrict__ WTa, const bf16* __restrict__ WT2,
    const float* __restrict__ ub2, const float* __restrict__ lnw,
    const float* __restrict__ lnb, float* __restrict__ Sout)
{
  __shared__ __align__(16) bf16 Sbf[64*SROW];   // 33792 B
  __shared__ __align__(16) bf16 Hbf[64*HROW];   // 66560 B
  __shared__ float redA[64*8], redB[64*8];      // 4 KB

  int tid = threadIdx.x;
  int w   = tid >> 6;        // 0..7
  int lane= tid & 63;
  int l15 = lane & 15;
  int l4  = lane >> 4;       // 0..3
  int row0 = blockIdx.x * 64;

  // GEMM2/N=256 ownership: wave w owns cols [w*32, w*32+32): nt<2
  f32x4 Sreg[4][2];
  float ub[2], lw[2], lb[2];
  #pragma unroll
  for(int nt=0;nt<2;nt++){
    int col = w*32 + nt*16 + l15;
    ub[nt] = ub2[col]; lw[nt] = lnw[col]; lb[nt] = lnb[col];
  }
  #pragma unroll
  for(int mt=0;mt<4;mt++)
  #pragma unroll
  for(int nt=0;nt<2;nt++){
    int col = w*32 + nt*16 + l15;
    #pragma unroll
    for(int reg=0;reg<4;reg++){
      int r = mt*16 + l4*4 + reg;
      int node = (row0 + r) & 255;
      float v = Sini[node*256 + col];
      Sreg[mt][nt][reg] = v;
      Sbf[r*SROW + col] = __float2bfloat16(v);
    }
  }
  __syncthreads();

  const float* CpreBlk = Cpre + (size_t)row0*512;

  for(int step=0; step<NSTEPS; step++){
    // ---- GEMM1: H(64x512) = gelu(Sbf @ W1a + Cpre) ; wave w owns cols [w*64, w*64+64)
    f32x4 acc1[4][4];
    #pragma unroll
    for(int mt=0;mt<4;mt++)
    #pragma unroll
    for(int nt=0;nt<4;nt++) acc1[mt][nt] = (f32x4){0.f,0.f,0.f,0.f};
    const bf16* bp1[4];
    #pragma unroll
    for(int nt=0;nt<4;nt++) bp1[nt] = WTa + (size_t)(w*64 + nt*16 + l15)*256;
    for(int kc=0;kc<8;kc++){
      int k0 = kc*32 + l4*8;
      bf16x8 a[4];
      #pragma unroll
      for(int mt=0;mt<4;mt++) a[mt] = *(const bf16x8*)&Sbf[(mt*16 + l15)*SROW + k0];
      #pragma unroll
      for(int nt=0;nt<4;nt++){
        bf16x8 bfr = *(const bf16x8*)(bp1[nt] + k0);
        #pragma unroll
        for(int mt=0;mt<4;mt++)
          acc1[mt][nt] = __builtin_amdgcn_mfma_f32_16x16x32_bf16(a[mt], bfr, acc1[mt][nt], 0,0,0);
      }
    }
    #pragma unroll
    for(int nt=0;nt<4;nt++){
      int n = w*64 + nt*16 + l15;
      #pragma unroll
      for(int mt=0;mt<4;mt++)
      #pragma unroll
      for(int reg=0;reg<4;reg++){
        int r = mt*16 + l4*4 + reg;
        float cp = __builtin_nontemporal_load(&CpreBlk[(size_t)r*512 + n]);
        Hbf[r*HROW + n] = __float2bfloat16(geluf(acc1[mt][nt][reg] + cp));
      }
    }
    __syncthreads();   // Hbf ready; Sbf reads done

    // ---- GEMM2: u(64x256) = Hbf @ W2 ; wave w owns cols [w*32, w*32+32)
    f32x4 acc2[4][2];
    #pragma unroll
    for(int mt=0;mt<4;mt++)
    #pragma unroll
    for(int nt=0;nt<2;nt++) acc2[mt][nt] = (f32x4){0.f,0.f,0.f,0.f};
    const bf16* bp2[2];
    #pragma unroll
    for(int nt=0;nt<2;nt++) bp2[nt] = WT2 + (size_t)(w*32 + nt*16 + l15)*512;
    for(int kc=0;kc<16;kc++){
      int k0 = kc*32 + l4*8;
      bf16x8 a[4];
      #pragma unroll
      for(int mt=0;mt<4;mt++) a[mt] = *(const bf16x8*)&Hbf[(mt*16 + l15)*HROW + k0];
      #pragma unroll
      for(int nt=0;nt<2;nt++){
        bf16x8 bfr = *(const bf16x8*)(bp2[nt] + k0);
        #pragma unroll
        for(int mt=0;mt<4;mt++)
          acc2[mt][nt] = __builtin_amdgcn_mfma_f32_16x16x32_bf16(a[mt], bfr, acc2[mt][nt], 0,0,0);
      }
    }
    // ---- residual + LN partials
    #pragma unroll
    for(int mt=0;mt<4;mt++)
    #pragma unroll
    for(int nt=0;nt<2;nt++)
    #pragma unroll
    for(int reg=0;reg<4;reg++)
      acc2[mt][nt][reg] = Sreg[mt][nt][reg] + acc2[mt][nt][reg] + ub[nt];

    #pragma unroll
    for(int mt=0;mt<4;mt++)
    #pragma unroll
    for(int reg=0;reg<4;reg++){
      float s1 = 0.f, s2 = 0.f;
      #pragma unroll
      for(int nt=0;nt<2;nt++){ float v = acc2[mt][nt][reg]; s1 += v; s2 += v*v; }
      #pragma unroll
      for(int o=1;o<16;o<<=1){ s1 += __shfl_xor(s1,o); s2 += __shfl_xor(s2,o); }
      if(l15 == 0){
        int r = mt*16 + l4*4 + reg;
        redA[r*8+w] = s1; redB[r*8+w] = s2;
      }
    }
    __syncthreads();   // red ready; Hbf reads done

    #pragma unroll
    for(int mt=0;mt<4;mt++)
    #pragma unroll
    for(int reg=0;reg<4;reg++){
      int r = mt*16 + l4*4 + reg;
      float ss = 0.f, qq = 0.f;
      #pragma unroll
      for(int i=0;i<8;i++){ ss += redA[r*8+i]; qq += redB[r*8+i]; }
      float mu = ss*(1.f/256.f);
      float rs = rsqrtf(qq*(1.f/256.f) - mu*mu + 1e-5f);
      #pragma unroll
      for(int nt=0;nt<2;nt++){
        int col = w*32 + nt*16 + l15;
        float sv = (acc2[mt][nt][reg]-mu)*rs*lw[nt] + lb[nt];
        Sreg[mt][nt][reg] = sv;
        Sbf[r*SROW + col] = __float2bfloat16(sv);
      }
    }
    __syncthreads();   // Sbf ready for next step
  }

  // write final S (fp32) for the head
  #pragma unroll
  for(int mt=0;mt<4;mt++)
  #pragma unroll
  for(int nt=0;nt<2;nt++){
    int col = w*32 + nt*16 + l15;
    #pragma unroll
    for(int reg=0;reg<4;reg++){
      int r = mt*16 + l4*4 + reg;
      Sout[(size_t)(row0+r)*256 + col] = Sreg[mt][nt][reg];
    }
  }
}

// ---------------- head
__global__ __launch_bounds__(256) void k_head(const int* __restrict__ qsrc, const int* __restrict__ qtgt,
    const float* __restrict__ S, const float* __restrict__ hw1, const float* __restrict__ hb1,
    const float* __restrict__ hw2, const float* __restrict__ hb2, float* __restrict__ out){
  __shared__ float a[512];
  __shared__ float h[256];
  __shared__ float rbuf[8];
  int b = blockIdx.x, j = threadIdx.x;
  int s = min(max(qsrc[b],0),255), t = min(max(qtgt[b],0),255);
  a[j]     = S[((size_t)b*NNODE + s)*256 + j];
  a[256+j] = S[((size_t)b*NNODE + t)*256 + j];
  __syncthreads();
  float acc = hb1[j];
  for(int k=0;k<512;k++) acc += a[k]*hw1[k*256+j];
  h[j] = geluf(acc);
  __syncthreads();
  float p0 = h[j]*hw2[j*2], p1 = h[j]*hw2[j*2+1];
  for(int o=32;o>0;o>>=1){ p0 += __shfl_down(p0,o); p1 += __shfl_down(p1,o); }
  if((j&63)==0){ rbuf[(j>>6)*2] = p0; rbuf[(j>>6)*2+1] = p1; }
  __syncthreads();
  if(j==0){
    out[b*2+0] = rbuf[0]+rbuf[2]+rbuf[4]+rbuf[6] + hb2[0];
    out[b*2+1] = rbuf[1]+rbuf[3]+rbuf[5]+rbuf[7] + hb2[1];
  }
}

extern "C" void kernel_launch(void* const* d_in, const int* in_sizes, int n_in,
                              void* d_out, int out_size, void* d_ws, size_t ws_size,
                              hipStream_t stream){
  (void)in_sizes; (void)n_in; (void)out_size; (void)ws_size;
  const int*  src  = (const int*)d_in[0];
  const int*  rel  = (const int*)d_in[1];
  const int*  tgt  = (const int*)d_in[2];
  const int*  qsrc = (const int*)d_in[4];
  const int*  qtgt = (const int*)d_in[5];
  const float* ne  = (const float*)d_in[6];
  const float* re  = (const float*)d_in[7];
  const float* ew1 = (const float*)d_in[8];  const float* eb1 = (const float*)d_in[9];
  const float* ew2 = (const float*)d_in[10]; const float* eb2 = (const float*)d_in[11];
  const float* qw1 = (const float*)d_in[12]; const float* qb1 = (const float*)d_in[13];
  const float* qw2 = (const float*)d_in[14]; const float* qb2 = (const float*)d_in[15];
  const float* gp  = (const float*)d_in[16]; const float* sp  = (const float*)d_in[17];
  const float* mw1 = (const float*)d_in[18]; const float* mb1 = (const float*)d_in[19];
  const float* mw2 = (const float*)d_in[20]; const float* mb2 = (const float*)d_in[21];
  const float* gw1 = (const float*)d_in[22]; const float* gb1 = (const float*)d_in[23];
  const float* gw2 = (const float*)d_in[24]; const float* gb2 = (const float*)d_in[25];
  const float* uw1 = (const float*)d_in[26]; const float* ub1 = (const float*)d_in[27];
  const float* uw2 = (const float*)d_in[28]; const float* ub2 = (const float*)d_in[29];
  const float* lnw = (const float*)d_in[30]; const float* lnb = (const float*)d_in[31];
  const float* Sini= (const float*)d_in[32];
  const float* hw1 = (const float*)d_in[33]; const float* hb1 = (const float*)d_in[34];
  const float* hw2 = (const float*)d_in[35]; const float* hb2 = (const float*)d_in[36];

  float* ws = (float*)d_ws;
  float* P        = ws;                  //    26112
  float* qv       = ws + 26112;          //    16384
  float* incoming = ws + 42496;          //  4194304
  float* Cpre     = ws + 4236800;        //  8388608
  float* Sout     = ws + 12625408;       //  4194304
  bf16*  wb       = (bf16*)(ws + 16819712);
  bf16*  WTa = wb;            bf16* WT2 = wb + 131072;
  bf16*  Weh = wb + 262144;   bf16* Wel = wb + 327680;
  bf16*  Wg  = wb + 393216;
  bf16*  Wm1 = wb + 458752;   bf16* Wm2 = wb + 589824;
  float* out = (float*)d_out;

  hipMemsetAsync(incoming, 0, (size_t)4194304*4, stream);
  k_wprep<<<512,256,0,stream>>>(uw1,uw2,ew2,gw1,mw1,mw2,WTa,WT2,Weh,Wel,Wg,Wm1,Wm2);
  k_precompute<<<102,256,0,stream>>>(ne,re,ew1,eb1,P);
  k_query<<<64,256,0,stream>>>(qsrc,qtgt,ne,qw1,qb1,qw2,qb2,qv);
  k_edge_mfma<<<4096,256,0,stream>>>(src,rel,tgt,P,Weh,Wel,eb2,Wg,gb1,gw2,gb2,gp,sp,Wm1,mb1,Wm2,mb2,incoming);
  k_qrow<<<64,256,0,stream>>>(qv,mw1,mb1,mw2,mb2,gw1,gb1,gw2,gb2,gp,sp,incoming);
  k_cpre<<<512,256,0,stream>>>(incoming,uw1,ub1,Cpre);
  k_steps<<<256,512,0,stream>>>(Sini,Cpre,WTa,WT2,ub2,lnw,lnb,Sout);
  k_head<<<64,256,0,stream>>>(qsrc,qtgt,Sout,hw1,hb1,hw2,hb2,out);
}

// Round 6
// 2929.940 us; speedup vs baseline: 2.9824x; 1.1354x over previous
//
#include <hip/hip_runtime.h>
#include <hip/hip_bf16.h>
#include <math.h>

#define NB     64
#define LL     2048
#define DD     256
#define NNODE  256     // G*K
#define NSTEPS 32

typedef __hip_bfloat16 bf16;
typedef __attribute__((ext_vector_type(8))) short bf16x8;
typedef __attribute__((ext_vector_type(4))) float f32x4;

__device__ __forceinline__ float geluf(float x){ return 0.5f*x*(1.0f+erff(x*0.70710678118654752440f)); }
__device__ __forceinline__ short f2bs(float x){ bf16 h = __float2bfloat16(x); return __builtin_bit_cast(short, h); }
__device__ __forceinline__ float bs2f(short s){ bf16 h = __builtin_bit_cast(bf16, s); return __bfloat162float(h); }

// build bf16 hi/lo split fragment from 8 fp32 values
__device__ __forceinline__ void split8(float4 a, float4 b, bf16x8& hi, bf16x8& lo){
  float av[8] = {a.x,a.y,a.z,a.w,b.x,b.y,b.z,b.w};
  #pragma unroll
  for(int j=0;j<8;j++){
    short h = f2bs(av[j]);
    hi[j] = h;
    lo[j] = f2bs(av[j] - bs2f(h));
  }
}
__device__ __forceinline__ bf16x8 cvt8(float4 a, float4 b){
  float av[8] = {a.x,a.y,a.z,a.w,b.x,b.y,b.z,b.w};
  bf16x8 v;
  #pragma unroll
  for(int j=0;j<8;j++) v[j] = f2bs(av[j]);
  return v;
}

// ---------------- K1: P tables: rows 0..49 src-part, 50..51 rel-part(+eb1), 52..101 tgt-part
__global__ __launch_bounds__(256) void k_precompute(const float* __restrict__ ne,
    const float* __restrict__ re, const float* __restrict__ ew1, const float* __restrict__ eb1,
    float* __restrict__ P){
  __shared__ float a[256];
  int row = blockIdx.x, j = threadIdx.x;
  const float* vec; const float* W;
  if(row < 50){ vec = ne + row*256; W = ew1; }
  else if(row < 52){ vec = re + (row-50)*256; W = ew1 + 256*256; }
  else { vec = ne + (row-52)*256; W = ew1 + 512*256; }
  a[j] = vec[j];
  __syncthreads();
  float acc = 0.f;
  for(int k=0;k<256;k++) acc += a[k]*W[k*256 + j];
  if(row >= 50 && row < 52) acc += eb1[j];
  P[row*256 + j] = acc;
}

// ---------------- K2: q[b] = MLP2(concat(ne[qsrc], ne[qtgt]))
__global__ __launch_bounds__(256) void k_query(const int* __restrict__ qsrc, const int* __restrict__ qtgt,
    const float* __restrict__ ne, const float* __restrict__ qw1, const float* __restrict__ qb1,
    const float* __restrict__ qw2, const float* __restrict__ qb2, float* __restrict__ qv){
  __shared__ float a[512];
  __shared__ float h[256];
  int b = blockIdx.x, j = threadIdx.x;
  int s = min(max(qsrc[b],0),49), t = min(max(qtgt[b],0),49);
  a[j]     = ne[s*256 + j];
  a[256+j] = ne[t*256 + j];
  __syncthreads();
  float acc = qb1[j];
  for(int k=0;k<512;k++) acc += a[k]*qw1[k*256+j];
  h[j] = geluf(acc);
  __syncthreads();
  float acc2 = qb2[j];
  for(int k=0;k<256;k++) acc2 += h[k]*qw2[k*256+j];
  qv[b*256+j] = acc2;
}

// ---------------- weight prep: all transposed [n][k] bf16 (hi, and hi/lo for ew2)
__global__ __launch_bounds__(256) void k_wprep(
    const float* __restrict__ uw1, const float* __restrict__ uw2,
    const float* __restrict__ ew2, const float* __restrict__ gw1,
    const float* __restrict__ mw1, const float* __restrict__ mw2,
    bf16* __restrict__ WTa, bf16* __restrict__ WT2,
    bf16* __restrict__ Weh, bf16* __restrict__ Wel, bf16* __restrict__ Wg,
    bf16* __restrict__ Wm1, bf16* __restrict__ Wm2){
  int i = blockIdx.x*256 + threadIdx.x;   // 0 .. 131071
  { int n = i >> 8, k = i & 255;  WTa[i] = __float2bfloat16(uw1[k*512 + n]); }
  { int n = i >> 9, k = i & 511;  WT2[i] = __float2bfloat16(uw2[k*256 + n]); }
  { int n = i >> 8, k = i & 255;  Wm1[i] = __float2bfloat16(mw1[k*512 + n]); }
  { int n = i >> 9, k = i & 511;  Wm2[i] = __float2bfloat16(mw2[k*256 + n]); }
  if(i < 65536){
    int n = i >> 8, k = i & 255;
    float v = ew2[k*256 + n];
    bf16 h = __float2bfloat16(v);
    Weh[i] = h;
    Wel[i] = __float2bfloat16(v - __bfloat162float(h));
    Wg[i]  = __float2bfloat16(gw1[k*256 + n]);
  }
}

// ---------------- K4: MFMA edge pipeline: gather->edge GEMM(split)->gate/route->msg->scatter
#define AST 260   // fp32 LDS row stride (1040B: 16B-aligned, bank-balanced)
#define MST 520   // bf16 LDS row stride (1040B)
__global__ __launch_bounds__(256,2) void k_edge_mfma(
    const int* __restrict__ src, const int* __restrict__ rel, const int* __restrict__ tgt,
    const float* __restrict__ P,
    const bf16* __restrict__ Weh, const bf16* __restrict__ Wel, const float* __restrict__ eb2,
    const bf16* __restrict__ Wg, const float* __restrict__ gb1,
    const float* __restrict__ gw2, const float* __restrict__ gb2,
    const float* __restrict__ gp, const float* __restrict__ sp,
    const bf16* __restrict__ Wm1, const float* __restrict__ mb1,
    const bf16* __restrict__ Wm2, const float* __restrict__ mb2,
    float* __restrict__ incoming)
{
  __shared__ __align__(16) float Af[32*AST];   // fp32 gelu'd edge-hidden; overlaid by Mh (bf16) from E1 on
  __shared__ __align__(16) float Xf[32*AST];   // fp32 Xe
  __shared__ float pv[32*32];
  __shared__ float redG[32*4];
  __shared__ float gatev[32];
  __shared__ int   nidx[32];
  bf16* Mh = (bf16*)Af;    // 32*520*2 B == 32*260*4 B exactly

  int tid = threadIdx.x;
  int w = tid>>6, lane = tid&63, l15 = lane&15, l4 = lane>>4;
  int blk = blockIdx.x, b = blk>>6, r0 = (blk&63)*32;

  // ---- phase A: gather P rows + gelu -> Af [row][k] fp32
  {
    int rr = tid&31, kb = (tid>>5)*32;
    int gr = b*LL + r0 + rr;
    int s = min(max(src[gr],0),49), rl = rel[gr]&1, t = min(max(tgt[gr],0),49);
    const float* ps = P + s*256;
    const float* pr = P + (50+rl)*256;
    const float* pt = P + (52+t)*256;
    #pragma unroll
    for(int j=0;j<32;j+=4){
      int k = kb+j;
      float4 vs = *(const float4*)(ps+k), vr = *(const float4*)(pr+k), vt = *(const float4*)(pt+k);
      float4 o;
      o.x = geluf(vs.x+vr.x+vt.x); o.y = geluf(vs.y+vr.y+vt.y);
      o.z = geluf(vs.z+vr.z+vt.z); o.w = geluf(vs.w+vr.w+vt.w);
      *(float4*)&Af[rr*AST + k] = o;
    }
  }
  __syncthreads();

  // ---- phase B: Xe = A @ ew2 + eb2, fp32-faithful via hi/lo split (3 MFMA terms)
  {
    f32x4 acc[2][4];
    #pragma unroll
    for(int mt=0;mt<2;mt++)
    #pragma unroll
    for(int nt=0;nt<4;nt++) acc[mt][nt] = (f32x4){0.f,0.f,0.f,0.f};
    for(int kc=0;kc<8;kc++){
      int k0 = kc*32 + l4*8;
      bf16x8 ah[2], al[2];
      #pragma unroll
      for(int mt=0;mt<2;mt++){
        const float* p = &Af[(mt*16+l15)*AST + k0];
        split8(*(const float4*)p, *(const float4*)(p+4), ah[mt], al[mt]);
      }
      #pragma unroll
      for(int nt=0;nt<4;nt++){
        int n = w*64 + nt*16 + l15;
        bf16x8 wh = *(const bf16x8*)&Weh[n*256 + k0];
        bf16x8 wl = *(const bf16x8*)&Wel[n*256 + k0];
        #pragma unroll
        for(int mt=0;mt<2;mt++){
          acc[mt][nt] = __builtin_amdgcn_mfma_f32_16x16x32_bf16(ah[mt], wh, acc[mt][nt], 0,0,0);
          acc[mt][nt] = __builtin_amdgcn_mfma_f32_16x16x32_bf16(ah[mt], wl, acc[mt][nt], 0,0,0);
          acc[mt][nt] = __builtin_amdgcn_mfma_f32_16x16x32_bf16(al[mt], wh, acc[mt][nt], 0,0,0);
        }
      }
    }
    #pragma unroll
    for(int nt=0;nt<4;nt++){
      int n = w*64 + nt*16 + l15;
      float bb = eb2[n];
      #pragma unroll
      for(int mt=0;mt<2;mt++)
      #pragma unroll
      for(int reg=0;reg<4;reg++){
        int r = mt*16 + l4*4 + reg;
        Xf[r*AST + n] = acc[mt][nt][reg] + bb;
      }
    }
  }
  __syncthreads();

  // ---- phase C: gate hidden (bf16 MFMA) + inline gate dot -> redG
  {
    f32x4 ag[2][4];
    #pragma unroll
    for(int mt=0;mt<2;mt++)
    #pragma unroll
    for(int nt=0;nt<4;nt++) ag[mt][nt] = (f32x4){0.f,0.f,0.f,0.f};
    for(int kc=0;kc<8;kc++){
      int k0 = kc*32 + l4*8;
      bf16x8 xa[2];
      #pragma unroll
      for(int mt=0;mt<2;mt++){
        const float* p = &Xf[(mt*16+l15)*AST + k0];
        xa[mt] = cvt8(*(const float4*)p, *(const float4*)(p+4));
      }
      #pragma unroll
      for(int nt=0;nt<4;nt++){
        int n = w*64 + nt*16 + l15;
        bf16x8 wv = *(const bf16x8*)&Wg[n*256 + k0];
        #pragma unroll
        for(int mt=0;mt<2;mt++)
          ag[mt][nt] = __builtin_amdgcn_mfma_f32_16x16x32_bf16(xa[mt], wv, ag[mt][nt], 0,0,0);
      }
    }
    float gpart[2][4] = {{0.f,0.f,0.f,0.f},{0.f,0.f,0.f,0.f}};
    #pragma unroll
    for(int nt=0;nt<4;nt++){
      int n = w*64 + nt*16 + l15;
      float gb = gb1[n], gw = gw2[n];
      #pragma unroll
      for(int mt=0;mt<2;mt++)
      #pragma unroll
      for(int reg=0;reg<4;reg++)
        gpart[mt][reg] += geluf(ag[mt][nt][reg] + gb)*gw;
    }
    #pragma unroll
    for(int mt=0;mt<2;mt++)
    #pragma unroll
    for(int reg=0;reg<4;reg++){
      float sv = gpart[mt][reg];
      #pragma unroll
      for(int o=1;o<16;o<<=1) sv += __shfl_xor(sv,o);
      if(l15==0) redG[(mt*16 + l4*4 + reg)*4 + w] = sv;
    }
  }
  // ---- phase D: routing projections (fp32, from fp32 Xe)
  {
    int r2 = tid>>3, g = tid&7, c0 = g*4;
    const float* W4 = (c0<16)? (gp + c0) : (sp + (c0-16));
    float4 p = {0.f,0.f,0.f,0.f};
    for(int k=0;k<256;k++){
      float x = Xf[r2*AST + k];
      float4 wv = *(const float4*)(W4 + k*16);
      p.x += x*wv.x; p.y += x*wv.y; p.z += x*wv.z; p.w += x*wv.w;
    }
    pv[r2*32+c0+0]=p.x; pv[r2*32+c0+1]=p.y; pv[r2*32+c0+2]=p.z; pv[r2*32+c0+3]=p.w;
  }
  __syncthreads();
  if(tid < 32){
    float ssum = redG[tid*4+0]+redG[tid*4+1]+redG[tid*4+2]+redG[tid*4+3] + gb2[0];
    gatev[tid] = 1.f/(1.f+expf(-ssum));
    float bg = pv[tid*32+0]; int big = 0;
    #pragma unroll
    for(int j=1;j<16;j++){ float x=pv[tid*32+j]; if(x>bg){bg=x;big=j;} }
    float bs = pv[tid*32+16]; int bis = 0;
    #pragma unroll
    for(int j=1;j<16;j++){ float x=pv[tid*32+16+j]; if(x>bs){bs=x;bis=j;} }
    nidx[tid] = big*16 + bis;
  }
  __syncthreads();

  // ---- phase E1: msg hidden (N=512) -> Mh bf16 (overlays Af)
  {
    f32x4 a1[2][8];
    #pragma unroll
    for(int mt=0;mt<2;mt++)
    #pragma unroll
    for(int nt=0;nt<8;nt++) a1[mt][nt] = (f32x4){0.f,0.f,0.f,0.f};
    for(int kc=0;kc<8;kc++){
      int k0 = kc*32 + l4*8;
      bf16x8 xa[2];
      #pragma unroll
      for(int mt=0;mt<2;mt++){
        const float* p = &Xf[(mt*16+l15)*AST + k0];
        xa[mt] = cvt8(*(const float4*)p, *(const float4*)(p+4));
      }
      #pragma unroll
      for(int nt=0;nt<8;nt++){
        int n = w*128 + nt*16 + l15;
        bf16x8 wv = *(const bf16x8*)&Wm1[n*256 + k0];
        #pragma unroll
        for(int mt=0;mt<2;mt++)
          a1[mt][nt] = __builtin_amdgcn_mfma_f32_16x16x32_bf16(xa[mt], wv, a1[mt][nt], 0,0,0);
      }
    }
    __syncthreads();   // all Af-region reads long done; now safe to overwrite with Mh
    #pragma unroll
    for(int nt=0;nt<8;nt++){
      int n = w*128 + nt*16 + l15;
      float mb = mb1[n];
      #pragma unroll
      for(int mt=0;mt<2;mt++)
      #pragma unroll
      for(int reg=0;reg<4;reg++){
        int r = mt*16 + l4*4 + reg;
        Mh[r*MST + n] = __float2bfloat16(geluf(a1[mt][nt][reg] + mb));
      }
    }
  }
  __syncthreads();

  // ---- phase E2: msg out (K=512) + phase F scatter
  {
    f32x4 a2[2][4];
    #pragma unroll
    for(int mt=0;mt<2;mt++)
    #pragma unroll
    for(int nt=0;nt<4;nt++) a2[mt][nt] = (f32x4){0.f,0.f,0.f,0.f};
    for(int kc=0;kc<16;kc++){
      int k0 = kc*32 + l4*8;
      bf16x8 ha[2];
      #pragma unroll
      for(int mt=0;mt<2;mt++) ha[mt] = *(const bf16x8*)&Mh[(mt*16+l15)*MST + k0];
      #pragma unroll
      for(int nt=0;nt<4;nt++){
        int n = w*64 + nt*16 + l15;
        bf16x8 wv = *(const bf16x8*)&Wm2[n*512 + k0];
        #pragma unroll
        for(int mt=0;mt<2;mt++)
          a2[mt][nt] = __builtin_amdgcn_mfma_f32_16x16x32_bf16(ha[mt], wv, a2[mt][nt], 0,0,0);
      }
    }
    #pragma unroll
    for(int nt=0;nt<4;nt++){
      int col = w*64 + nt*16 + l15;
      float mb = mb2[col];
      #pragma unroll
      for(int mt=0;mt<2;mt++)
      #pragma unroll
      for(int reg=0;reg<4;reg++){
        int r = mt*16 + l4*4 + reg;
        float val = (a2[mt][nt][reg] + mb)*gatev[r];
        atomicAdd(&incoming[((size_t)b*NNODE + nidx[r])*256 + col], val);
      }
    }
  }
}

// ---------------- K5: the 64 q-rows through msg/gate/route/scatter
__global__ __launch_bounds__(256) void k_qrow(const float* __restrict__ qv,
    const float* __restrict__ mw1, const float* __restrict__ mb1,
    const float* __restrict__ mw2, const float* __restrict__ mb2,
    const float* __restrict__ gw1, const float* __restrict__ gb1,
    const float* __restrict__ gw2, const float* __restrict__ gb2,
    const float* __restrict__ gp, const float* __restrict__ sp,
    float* __restrict__ incoming){
  __shared__ float x[256];
  __shared__ float mh[512];
  __shared__ float gh[256];
  __shared__ float pv[32];
  __shared__ float rbuf[4];
  __shared__ float gv;
  __shared__ int nn;
  int b = blockIdx.x, j = threadIdx.x;
  x[j] = qv[b*256+j];
  __syncthreads();
  float a0 = mb1[j], a1 = mb1[256+j], g0 = gb1[j];
  for(int k=0;k<256;k++){
    float xv = x[k];
    a0 += xv*mw1[k*512+j];
    a1 += xv*mw1[k*512+256+j];
    g0 += xv*gw1[k*256+j];
  }
  mh[j] = geluf(a0); mh[256+j] = geluf(a1); gh[j] = geluf(g0);
  if(j < 32){
    float s1 = 0.f;
    const float* wq = (j<16)? gp+j : sp+(j-16);
    for(int k=0;k<256;k++) s1 += x[k]*wq[k*16];
    pv[j] = s1;
  }
  __syncthreads();
  float m0 = mb2[j];
  for(int k=0;k<512;k++) m0 += mh[k]*mw2[k*256+j];
  float part = gh[j]*gw2[j];
  for(int o=32;o>0;o>>=1) part += __shfl_down(part,o);
  if((j&63)==0) rbuf[j>>6] = part;
  __syncthreads();
  if(j==0){
    float s1 = rbuf[0]+rbuf[1]+rbuf[2]+rbuf[3];
    gv = 1.f/(1.f+expf(-(s1 + gb2[0])));
    float bg = pv[0]; int big = 0;
    for(int t2=1;t2<16;t2++){ if(pv[t2]>bg){bg=pv[t2];big=t2;} }
    float bs = pv[16]; int bis = 0;
    for(int t2=1;t2<16;t2++){ if(pv[16+t2]>bs){bs=pv[16+t2];bis=t2;} }
    nn = big*16 + bis;
  }
  __syncthreads();
  atomicAdd(&incoming[((size_t)b*NNODE + nn)*256 + j], m0*gv);
}

// ---------------- K6: Cpre = incoming @ upd_w1[256:512] + upd_b1   (fp32, loop-invariant)
__device__ __forceinline__ void fma32_2q(const float* Arow, float w0, float w1, float* acc0, float* acc1){
  const float4* ap = (const float4*)Arow;
  #pragma unroll
  for(int i=0;i<8;i++){
    float4 a = ap[i];
    acc0[i*4+0] += a.x*w0; acc0[i*4+1] += a.y*w0;
    acc0[i*4+2] += a.z*w0; acc0[i*4+3] += a.w*w0;
    acc1[i*4+0] += a.x*w1; acc1[i*4+1] += a.y*w1;
    acc1[i*4+2] += a.z*w1; acc1[i*4+3] += a.w*w1;
  }
}
__global__ __launch_bounds__(256,2) void k_cpre(const float* __restrict__ incoming,
    const float* __restrict__ uw1, const float* __restrict__ ub1, float* __restrict__ Cpre){
  __shared__ float ATl[256*32];
  int blk = blockIdx.x, row0 = blk*32;
  int tid = threadIdx.x, rr = tid&31, kb = (tid>>5)*32;
  const float* ip = incoming + (size_t)(row0+rr)*256;
  #pragma unroll
  for(int j=0;j<32;j+=4){
    float4 v = *(const float4*)(ip+kb+j);
    ATl[(kb+j+0)*32+rr]=v.x; ATl[(kb+j+1)*32+rr]=v.y;
    ATl[(kb+j+2)*32+rr]=v.z; ATl[(kb+j+3)*32+rr]=v.w;
  }
  __syncthreads();
  float acc0[32], acc1[32];
  #pragma unroll
  for(int r=0;r<32;r++){acc0[r]=0.f;acc1[r]=0.f;}
  int c = tid;
  float w0 = uw1[256*512 + c], w1 = uw1[256*512 + 256 + c];
  for(int k=0;k<256;k++){
    float w0n = (k<255)? uw1[(257+k)*512 + c] : 0.f;
    float w1n = (k<255)? uw1[(257+k)*512 + 256 + c] : 0.f;
    fma32_2q(&ATl[k*32], w0, w1, acc0, acc1);
    w0 = w0n; w1 = w1n;
  }
  float b0 = ub1[c], b1 = ub1[256+c];
  #pragma unroll
  for(int r=0;r<32;r++){
    size_t ro = (size_t)(row0+r)*512;
    Cpre[ro+c]     = acc0[r]+b0;
    Cpre[ro+256+c] = acc1[r]+b1;
  }
}

// ---------------- persistent 32-step update: MFMA bf16, fp32 state/LN
// M=64 rows/block, 512 threads (8 waves), grid 256, 1 block/CU.
// Cpre lives in REGISTERS (64 f32/thread, C-fragment layout) — zero per-step
// memory traffic for it; weights stay L2-resident. B-fragment loads are
// 2-stage software-pipelined to hide L2 latency.
#define SROW 264
#define HROW 520
__global__ __launch_bounds__(512,2) void k_steps(
    const float* __restrict__ Sini, const float* __restrict__ Cpre,
    const bf16* __restrict__ WTa, const bf16* __restrict__ WT2,
    const float* __restrict__ ub2, const float* __restrict__ lnw,
    const float* __restrict__ lnb, float* __restrict__ Sout)
{
  __shared__ __align__(16) bf16 Sbf[64*SROW];   // 33792 B
  __shared__ __align__(16) bf16 Hbf[64*HROW];   // 66560 B
  __shared__ float redA[64*8], redB[64*8];      // 4 KB

  int tid = threadIdx.x;
  int w   = tid >> 6;        // 0..7
  int lane= tid & 63;
  int l15 = lane & 15;
  int l4  = lane >> 4;       // 0..3
  int row0 = blockIdx.x * 64;

  // GEMM2/N=256 ownership: wave w owns cols [w*32, w*32+32): nt<2
  f32x4 Sreg[4][2];
  float ub[2], lw[2], lb[2];
  #pragma unroll
  for(int nt=0;nt<2;nt++){
    int col = w*32 + nt*16 + l15;
    ub[nt] = ub2[col]; lw[nt] = lnw[col]; lb[nt] = lnb[col];
  }
  #pragma unroll
  for(int mt=0;mt<4;mt++)
  #pragma unroll
  for(int nt=0;nt<2;nt++){
    int col = w*32 + nt*16 + l15;
    #pragma unroll
    for(int reg=0;reg<4;reg++){
      int r = mt*16 + l4*4 + reg;
      int node = (row0 + r) & 255;
      float v = Sini[node*256 + col];
      Sreg[mt][nt][reg] = v;
      Sbf[r*SROW + col] = __float2bfloat16(v);
    }
  }

  // ---- Cpre -> registers, GEMM1 C-fragment layout [mt][nt][reg]
  const float* CpreBlk = Cpre + (size_t)row0*512;
  f32x4 Creg[4][4];
  #pragma unroll
  for(int nt=0;nt<4;nt++){
    int n = w*64 + nt*16 + l15;
    #pragma unroll
    for(int mt=0;mt<4;mt++)
    #pragma unroll
    for(int reg=0;reg<4;reg++){
      int r = mt*16 + l4*4 + reg;
      Creg[mt][nt][reg] = CpreBlk[(size_t)r*512 + n];
    }
  }
  __syncthreads();

  const bf16* bp1[4];
  #pragma unroll
  for(int nt=0;nt<4;nt++) bp1[nt] = WTa + (size_t)(w*64 + nt*16 + l15)*256 + l4*8;
  const bf16* bp2[2];
  #pragma unroll
  for(int nt=0;nt<2;nt++) bp2[nt] = WT2 + (size_t)(w*32 + nt*16 + l15)*512 + l4*8;

  for(int step=0; step<NSTEPS; step++){
    // ---- GEMM1: H(64x512) = gelu(Sbf @ W1a + Creg) ; wave w owns cols [w*64, w*64+64)
    f32x4 acc1[4][4];
    #pragma unroll
    for(int mt=0;mt<4;mt++)
    #pragma unroll
    for(int nt=0;nt<4;nt++) acc1[mt][nt] = (f32x4){0.f,0.f,0.f,0.f};
    bf16x8 b1c[4], b1n[4];
    #pragma unroll
    for(int nt=0;nt<4;nt++) b1c[nt] = *(const bf16x8*)(bp1[nt]);
    for(int kc=0;kc<8;kc++){
      if(kc<7){
        #pragma unroll
        for(int nt=0;nt<4;nt++) b1n[nt] = *(const bf16x8*)(bp1[nt] + (kc+1)*32);
      }
      int k0 = kc*32 + l4*8;
      bf16x8 a[4];
      #pragma unroll
      for(int mt=0;mt<4;mt++) a[mt] = *(const bf16x8*)&Sbf[(mt*16 + l15)*SROW + k0];
      #pragma unroll
      for(int nt=0;nt<4;nt++)
      #pragma unroll
      for(int mt=0;mt<4;mt++)
        acc1[mt][nt] = __builtin_amdgcn_mfma_f32_16x16x32_bf16(a[mt], b1c[nt], acc1[mt][nt], 0,0,0);
      #pragma unroll
      for(int nt=0;nt<4;nt++) b1c[nt] = b1n[nt];
    }
    #pragma unroll
    for(int nt=0;nt<4;nt++){
      int n = w*64 + nt*16 + l15;
      #pragma unroll
      for(int mt=0;mt<4;mt++)
      #pragma unroll
      for(int reg=0;reg<4;reg++){
        int r = mt*16 + l4*4 + reg;
        Hbf[r*HROW + n] = __float2bfloat16(geluf(acc1[mt][nt][reg] + Creg[mt][nt][reg]));
      }
    }
    __syncthreads();   // Hbf ready; Sbf reads done

    // ---- GEMM2: u(64x256) = Hbf @ W2 ; wave w owns cols [w*32, w*32+32)
    f32x4 acc2[4][2];
    #pragma unroll
    for(int mt=0;mt<4;mt++)
    #pragma unroll
    for(int nt=0;nt<2;nt++) acc2[mt][nt] = (f32x4){0.f,0.f,0.f,0.f};
    bf16x8 b2c[2], b2n[2];
    #pragma unroll
    for(int nt=0;nt<2;nt++) b2c[nt] = *(const bf16x8*)(bp2[nt]);
    for(int kc=0;kc<16;kc++){
      if(kc<15){
        #pragma unroll
        for(int nt=0;nt<2;nt++) b2n[nt] = *(const bf16x8*)(bp2[nt] + (kc+1)*32);
      }
      int k0 = kc*32 + l4*8;
      bf16x8 a[4];
      #pragma unroll
      for(int mt=0;mt<4;mt++) a[mt] = *(const bf16x8*)&Hbf[(mt*16 + l15)*HROW + k0];
      #pragma unroll
      for(int nt=0;nt<2;nt++)
      #pragma unroll
      for(int mt=0;mt<4;mt++)
        acc2[mt][nt] = __builtin_amdgcn_mfma_f32_16x16x32_bf16(a[mt], b2c[nt], acc2[mt][nt], 0,0,0);
      #pragma unroll
      for(int nt=0;nt<2;nt++) b2c[nt] = b2n[nt];
    }
    // ---- residual + LN partials
    #pragma unroll
    for(int mt=0;mt<4;mt++)
    #pragma unroll
    for(int nt=0;nt<2;nt++)
    #pragma unroll
    for(int reg=0;reg<4;reg++)
      acc2[mt][nt][reg] = Sreg[mt][nt][reg] + acc2[mt][nt][reg] + ub[nt];

    #pragma unroll
    for(int mt=0;mt<4;mt++)
    #pragma unroll
    for(int reg=0;reg<4;reg++){
      float s1 = 0.f, s2 = 0.f;
      #pragma unroll
      for(int nt=0;nt<2;nt++){ float v = acc2[mt][nt][reg]; s1 += v; s2 += v*v; }
      #pragma unroll
      for(int o=1;o<16;o<<=1){ s1 += __shfl_xor(s1,o); s2 += __shfl_xor(s2,o); }
      if(l15 == 0){
        int r = mt*16 + l4*4 + reg;
        redA[r*8+w] = s1; redB[r*8+w] = s2;
      }
    }
    __syncthreads();   // red ready; Hbf reads done

    #pragma unroll
    for(int mt=0;mt<4;mt++)
    #pragma unroll
    for(int reg=0;reg<4;reg++){
      int r = mt*16 + l4*4 + reg;
      float ss = 0.f, qq = 0.f;
      #pragma unroll
      for(int i=0;i<8;i++){ ss += redA[r*8+i]; qq += redB[r*8+i]; }
      float mu = ss*(1.f/256.f);
      float rs = rsqrtf(qq*(1.f/256.f) - mu*mu + 1e-5f);
      #pragma unroll
      for(int nt=0;nt<2;nt++){
        int col = w*32 + nt*16 + l15;
        float sv = (acc2[mt][nt][reg]-mu)*rs*lw[nt] + lb[nt];
        Sreg[mt][nt][reg] = sv;
        Sbf[r*SROW + col] = __float2bfloat16(sv);
      }
    }
    __syncthreads();   // Sbf ready for next step
  }

  // write final S (fp32) for the head
  #pragma unroll
  for(int mt=0;mt<4;mt++)
  #pragma unroll
  for(int nt=0;nt<2;nt++){
    int col = w*32 + nt*16 + l15;
    #pragma unroll
    for(int reg=0;reg<4;reg++){
      int r = mt*16 + l4*4 + reg;
      Sout[(size_t)(row0+r)*256 + col] = Sreg[mt][nt][reg];
    }
  }
}

// ---------------- head
__global__ __launch_bounds__(256) void k_head(const int* __restrict__ qsrc, const int* __restrict__ qtgt,
    const float* __restrict__ S, const float* __restrict__ hw1, const float* __restrict__ hb1,
    const float* __restrict__ hw2, const float* __restrict__ hb2, float* __restrict__ out){
  __shared__ float a[512];
  __shared__ float h[256];
  __shared__ float rbuf[8];
  int b = blockIdx.x, j = threadIdx.x;
  int s = min(max(qsrc[b],0),255), t = min(max(qtgt[b],0),255);
  a[j]     = S[((size_t)b*NNODE + s)*256 + j];
  a[256+j] = S[((size_t)b*NNODE + t)*256 + j];
  __syncthreads();
  float acc = hb1[j];
  for(int k=0;k<512;k++) acc += a[k]*hw1[k*256+j];
  h[j] = geluf(acc);
  __syncthreads();
  float p0 = h[j]*hw2[j*2], p1 = h[j]*hw2[j*2+1];
  for(int o=32;o>0;o>>=1){ p0 += __shfl_down(p0,o); p1 += __shfl_down(p1,o); }
  if((j&63)==0){ rbuf[(j>>6)*2] = p0; rbuf[(j>>6)*2+1] = p1; }
  __syncthreads();
  if(j==0){
    out[b*2+0] = rbuf[0]+rbuf[2]+rbuf[4]+rbuf[6] + hb2[0];
    out[b*2+1] = rbuf[1]+rbuf[3]+rbuf[5]+rbuf[7] + hb2[1];
  }
}

extern "C" void kernel_launch(void* const* d_in, const int* in_sizes, int n_in,
                              void* d_out, int out_size, void* d_ws, size_t ws_size,
                              hipStream_t stream){
  (void)in_sizes; (void)n_in; (void)out_size; (void)ws_size;
  const int*  src  = (const int*)d_in[0];
  const int*  rel  = (const int*)d_in[1];
  const int*  tgt  = (const int*)d_in[2];
  const int*  qsrc = (const int*)d_in[4];
  const int*  qtgt = (const int*)d_in[5];
  const float* ne  = (const float*)d_in[6];
  const float* re  = (const float*)d_in[7];
  const float* ew1 = (const float*)d_in[8];  const float* eb1 = (const float*)d_in[9];
  const float* ew2 = (const float*)d_in[10]; const float* eb2 = (const float*)d_in[11];
  const float* qw1 = (const float*)d_in[12]; const float* qb1 = (const float*)d_in[13];
  const float* qw2 = (const float*)d_in[14]; const float* qb2 = (const float*)d_in[15];
  const float* gp  = (const float*)d_in[16]; const float* sp  = (const float*)d_in[17];
  const float* mw1 = (const float*)d_in[18]; const float* mb1 = (const float*)d_in[19];
  const float* mw2 = (const float*)d_in[20]; const float* mb2 = (const float*)d_in[21];
  const float* gw1 = (const float*)d_in[22]; const float* gb1 = (const float*)d_in[23];
  const float* gw2 = (const float*)d_in[24]; const float* gb2 = (const float*)d_in[25];
  const float* uw1 = (const float*)d_in[26]; const float* ub1 = (const float*)d_in[27];
  const float* uw2 = (const float*)d_in[28]; const float* ub2 = (const float*)d_in[29];
  const float* lnw = (const float*)d_in[30]; const float* lnb = (const float*)d_in[31];
  const float* Sini= (const float*)d_in[32];
  const float* hw1 = (const float*)d_in[33]; const float* hb1 = (const float*)d_in[34];
  const float* hw2 = (const float*)d_in[35]; const float* hb2 = (const float*)d_in[36];

  float* ws = (float*)d_ws;
  float* P        = ws;                  //    26112
  float* qv       = ws + 26112;          //    16384
  float* incoming = ws + 42496;          //  4194304
  float* Cpre     = ws + 4236800;        //  8388608
  float* Sout     = ws + 12625408;       //  4194304
  bf16*  wb       = (bf16*)(ws + 16819712);
  bf16*  WTa = wb;            bf16* WT2 = wb + 131072;
  bf16*  Weh = wb + 262144;   bf16* Wel = wb + 327680;
  bf16*  Wg  = wb + 393216;
  bf16*  Wm1 = wb + 458752;   bf16* Wm2 = wb + 589824;
  float* out = (float*)d_out;

  hipMemsetAsync(incoming, 0, (size_t)4194304*4, stream);
  k_wprep<<<512,256,0,stream>>>(uw1,uw2,ew2,gw1,mw1,mw2,WTa,WT2,Weh,Wel,Wg,Wm1,Wm2);
  k_precompute<<<102,256,0,stream>>>(ne,re,ew1,eb1,P);
  k_query<<<64,256,0,stream>>>(qsrc,qtgt,ne,qw1,qb1,qw2,qb2,qv);
  k_edge_mfma<<<4096,256,0,stream>>>(src,rel,tgt,P,Weh,Wel,eb2,Wg,gb1,gw2,gb2,gp,sp,Wm1,mb1,Wm2,mb2,incoming);
  k_qrow<<<64,256,0,stream>>>(qv,mw1,mb1,mw2,mb2,gw1,gb1,gw2,gb2,gp,sp,incoming);
  k_cpre<<<512,256,0,stream>>>(incoming,uw1,ub1,Cpre);
  k_steps<<<256,512,0,stream>>>(Sini,Cpre,WTa,WT2,ub2,lnw,lnb,Sout);
  k_head<<<64,256,0,stream>>>(qsrc,qtgt,Sout,hw1,hb1,hw2,hb2,out);
}